// Round 13
// baseline (687.422 us; speedup 1.0000x reference)
//
#include <hip/hip_runtime.h>
#include <hip/hip_bf16.h>
#include <math.h>

#define B_ 32
#define N_ 512
#define D_ 512
#define H_ 8
#define HD_ 64
#define QKV_ 1536
#define SCALE_ 0.125f

typedef unsigned short u16;
typedef unsigned int u32;
typedef __attribute__((ext_vector_type(8))) short bf16x8;
typedef __attribute__((ext_vector_type(4))) float f32x4;

#define GLOBAL_AS __attribute__((address_space(1)))
#define LDS_AS __attribute__((address_space(3)))

// ---------------- utility ----------------
__device__ __forceinline__ float gelu_f(float x) {
  float u = 0.7978845608028654f * (x + 0.044715f * x * x * x);
  u = fminf(fmaxf(u, -15.f), 15.f);
  float e = __expf(2.f * u);
  float th = 1.f - 2.f * __builtin_amdgcn_rcpf(e + 1.f);
  return 0.5f * x * (1.0f + th);
}

__device__ __forceinline__ u16 f2b(float f) {
  union { float f; u32 u; } v;
  v.f = f;
  u32 r = (v.u + 0x7FFFu + ((v.u >> 16) & 1u)) >> 16;
  return (u16)r;
}

__device__ __forceinline__ float b2f(u16 x) {
  union { u32 u; float f; } v;
  v.u = ((u32)x) << 16;
  return v.f;
}

// XCD-chunked bijective swizzle (m204)
__device__ __forceinline__ int xcd_swz(int orig, int nwg) {
  int q = nwg >> 3, r = nwg & 7;
  int xcd = orig & 7, idx = orig >> 3;
  return (xcd < r ? xcd * (q + 1) : r * (q + 1) + (xcd - r) * q) + idx;
}

// ---------------- fused prep: zero out0 + rope table + all weight transposes ----------------
__global__ void k_prep(const float* __restrict__ w_qkv, const float* __restrict__ w_o,
                       const float* __restrict__ w_ff1, const float* __restrict__ w_ff2,
                       u16* __restrict__ wq_t, u16* __restrict__ wo_t,
                       u16* __restrict__ wf1_t, u16* __restrict__ wf2_t,
                       float* __restrict__ out0, float2* __restrict__ tab) {
  __shared__ float tile[32][33];
  int bid = blockIdx.x;
  int t = threadIdx.x;
  if (bid < 64) {
    int idx = bid * 256 + t;
    out0[idx] = 0.f;
    int n = idx >> 5, i = idx & 31;
    float inv = powf(10000.0f, -(float)i * (1.0f / 32.0f));
    float f = (float)n * inv;
    float s, c;
    sincosf(f, &s, &c);
    tab[idx] = make_float2(c, s);
    return;
  }
  int b2 = bid - 64;
  const float* W;
  u16* Wt;
  int K, N;
  if (b2 < 2304) {
    int l = b2 / 768; b2 -= l * 768;
    W = w_qkv + (size_t)l * D_ * QKV_; Wt = wq_t + (size_t)l * QKV_ * D_;
    K = D_; N = QKV_;
  } else if (b2 < 2816) {
    b2 -= 2304; int l = b2 >> 8; b2 &= 255;
    W = w_o + (size_t)l * D_ * D_; Wt = wo_t + (size_t)l * D_ * D_;
    K = D_; N = D_;
  } else if (b2 < 4864) {
    b2 -= 2816; int l = b2 >> 10; b2 &= 1023;
    W = w_ff1 + (size_t)l * D_ * 4 * D_; Wt = wf1_t + (size_t)l * 4 * D_ * D_;
    K = D_; N = 4 * D_;
  } else {
    b2 -= 4864; int l = b2 >> 10; b2 &= 1023;
    W = w_ff2 + (size_t)l * 4 * D_ * D_; Wt = wf2_t + (size_t)l * D_ * 4 * D_;
    K = 4 * D_; N = D_;
  }
  int nbx = N >> 5;
  int bx = b2 % nbx, by = b2 / nbx;
  int k0 = by * 32, n0 = bx * 32;
  int r = t >> 3, c4 = (t & 7) * 4;
  float4 v = *(const float4*)&W[(size_t)(k0 + r) * N + n0 + c4];
  tile[r][c4] = v.x; tile[r][c4 + 1] = v.y; tile[r][c4 + 2] = v.z; tile[r][c4 + 3] = v.w;
  __syncthreads();
  ushort4 o;
  o.x = f2b(tile[c4 + 0][r]); o.y = f2b(tile[c4 + 1][r]);
  o.z = f2b(tile[c4 + 2][r]); o.w = f2b(tile[c4 + 3][r]);
  *(ushort4*)&Wt[(size_t)(n0 + r) * K + k0 + c4] = o;
}

// ---------------- embedding gather -> bf16 x ----------------
__global__ void k_embed(const int* __restrict__ ids, const float* __restrict__ emb,
                        u16* __restrict__ x) {
  int row = blockIdx.x;
  int id = ids[row];
  float4 v = ((const float4*)(emb + (size_t)id * D_))[threadIdx.x];
  ushort4 o;
  o.x = f2b(v.x); o.y = f2b(v.y); o.z = f2b(v.z); o.w = f2b(v.w);
  ((ushort4*)(x + (size_t)row * D_))[threadIdx.x] = o;
}

// ---------------- row LayerNorm over D=512, bf16 in/out, 4 rows/block ----------------
__global__ void k_ln(const u16* __restrict__ in, const float* __restrict__ gw,
                     const float* __restrict__ bw, u16* __restrict__ out) {
  int row = blockIdx.x * 4 + (threadIdx.x >> 6);
  int lane = threadIdx.x & 63;
  union { bf16x8 v; u16 s[8]; } u;
  u.v = *(const bf16x8*)(in + (size_t)row * D_ + lane * 8);
  float f[8];
#pragma unroll
  for (int j = 0; j < 8; ++j) f[j] = b2f(u.s[j]);
  float s = 0.f, q = 0.f;
#pragma unroll
  for (int j = 0; j < 8; ++j) { s += f[j]; q += f[j] * f[j]; }
#pragma unroll
  for (int o = 32; o >= 1; o >>= 1) {
    s += __shfl_xor(s, o);
    q += __shfl_xor(q, o);
  }
  float mean = s * (1.0f / D_);
  float var = q * (1.0f / D_) - mean * mean;
  float rstd = rsqrtf(var + 1e-5f);
  float4 g0 = *(const float4*)(gw + lane * 8);
  float4 g1 = *(const float4*)(gw + lane * 8 + 4);
  float4 b0 = *(const float4*)(bw + lane * 8);
  float4 b1 = *(const float4*)(bw + lane * 8 + 4);
  float gg[8] = {g0.x, g0.y, g0.z, g0.w, g1.x, g1.y, g1.z, g1.w};
  float bb[8] = {b0.x, b0.y, b0.z, b0.w, b1.x, b1.y, b1.z, b1.w};
  union { bf16x8 v; u16 s[8]; } ov;
#pragma unroll
  for (int j = 0; j < 8; ++j) ov.s[j] = f2b((f[j] - mean) * rstd * gg[j] + bb[j]);
  *(bf16x8*)(out + (size_t)row * D_ + lane * 8) = ov.v;
}

// ---------------- bf16 MFMA GEMM: 128x128, BK=64 (two 32-sub-tiles), dbuf ----------------
// resid/output x are bf16. Zero-conflict chunk-XOR swizzle (verified R10/R12).
template <int EPI, int BF16OUT>
__global__ __launch_bounds__(256) void k_mgemm(
    const u16* __restrict__ A, const u16* __restrict__ Bt,
    const float* __restrict__ bias, const u16* __restrict__ resid,
    void* __restrict__ Cv, int M, int K, int Nc, int nb0) {
  __shared__ u16 As[2][2][128 * 32];
  __shared__ u16 Bs[2][2][128 * 32];
  int t = threadIdx.x;
  int wave = t >> 6, lane = t & 63;
  int nwg = gridDim.x * gridDim.y;
  int swz = xcd_swz(blockIdx.y * gridDim.x + blockIdx.x, nwg);
  int m0 = (swz / gridDim.x) * 128;
  int n0 = ((swz % gridDim.x) + nb0) * 128;
  int wr = wave >> 1, wc = wave & 1;
  f32x4 acc[4][4] = {};

  int srow = lane >> 2;
  int scol = ((lane & 3) ^ ((lane >> 3) & 3)) * 8;
  const u16* gaBase = A + (size_t)(m0 + wave * 32 + srow) * K + scol;
  const u16* gbBase = Bt + (size_t)(n0 + wave * 32 + srow) * K + scol;

#define STAGE_MG(bsel, sub, kk)                                                \
  {                                                                            \
    _Pragma("unroll") for (int i_ = 0; i_ < 2; ++i_) {                         \
      int rbase_ = wave * 32 + i_ * 16;                                        \
      __builtin_amdgcn_global_load_lds(                                        \
          (const GLOBAL_AS void*)(gaBase + (size_t)(i_ * 16) * K + (kk)),      \
          (LDS_AS void*)&As[bsel][sub][rbase_ * 32], 16, 0, 0);                \
      __builtin_amdgcn_global_load_lds(                                        \
          (const GLOBAL_AS void*)(gbBase + (size_t)(i_ * 16) * K + (kk)),      \
          (LDS_AS void*)&Bs[bsel][sub][rbase_ * 32], 16, 0, 0);                \
    }                                                                          \
  }

  int c = lane & 15, g = lane >> 4;
  int chread = (g ^ ((c >> 1) & 3)) * 8;

  int nIter = K >> 6;
  STAGE_MG(0, 0, 0);
  STAGE_MG(0, 1, 32);
  __syncthreads();
  for (int it = 0; it < nIter; ++it) {
    int cur = it & 1;
    if (it + 1 < nIter) {
      STAGE_MG(cur ^ 1, 0, (size_t)(it + 1) * 64);
      STAGE_MG(cur ^ 1, 1, (size_t)(it + 1) * 64 + 32);
    }
#pragma unroll
    for (int sub = 0; sub < 2; ++sub) {
      const u16* as = As[cur][sub];
      const u16* bs = Bs[cur][sub];
      bf16x8 af[4], bfr[4];
#pragma unroll
      for (int mi = 0; mi < 4; ++mi)
        af[mi] = *(const bf16x8*)&as[(wr * 64 + mi * 16 + c) * 32 + chread];
#pragma unroll
      for (int ni = 0; ni < 4; ++ni)
        bfr[ni] = *(const bf16x8*)&bs[(wc * 64 + ni * 16 + c) * 32 + chread];
#pragma unroll
      for (int mi = 0; mi < 4; ++mi)
#pragma unroll
        for (int ni = 0; ni < 4; ++ni)
          acc[mi][ni] = __builtin_amdgcn_mfma_f32_16x16x32_bf16(bfr[ni], af[mi], acc[mi][ni], 0, 0, 0);
    }
    __syncthreads();
  }
#undef STAGE_MG

#pragma unroll
  for (int mi = 0; mi < 4; ++mi) {
    int m = m0 + wr * 64 + mi * 16 + (lane & 15);
    size_t rowoff = (size_t)m * Nc;
#pragma unroll
    for (int ni = 0; ni < 4; ++ni) {
      int n = n0 + wc * 64 + ni * 16 + (lane >> 4) * 4;
      float v0 = acc[mi][ni][0], v1 = acc[mi][ni][1],
            v2 = acc[mi][ni][2], v3 = acc[mi][ni][3];
      if (EPI == 2 || EPI == 3) {
        float4 bb = *(const float4*)&bias[n];
        v0 += bb.x; v1 += bb.y; v2 += bb.z; v3 += bb.w;
      }
      if (EPI == 2) {
        v0 = gelu_f(v0); v1 = gelu_f(v1); v2 = gelu_f(v2); v3 = gelu_f(v3);
      }
      if (EPI == 1 || EPI == 3) {
        ushort4 rr = *(const ushort4*)&resid[rowoff + n];
        v0 += b2f(rr.x); v1 += b2f(rr.y); v2 += b2f(rr.z); v3 += b2f(rr.w);
      }
      if (BF16OUT) {
        ushort4 o;
        o.x = f2b(v0); o.y = f2b(v1); o.z = f2b(v2); o.w = f2b(v3);
        *(ushort4*)&((u16*)Cv)[rowoff + n] = o;
      } else {
        *(float4*)&((float*)Cv)[rowoff + n] = make_float4(v0, v1, v2, v3);
      }
    }
  }
}

// ---------------- MFMA flash attention: paired q-tiles + async stage ----------------
__global__ __launch_bounds__(512) void k_fattn(const u16* __restrict__ qkv,
                                               const float2* __restrict__ tab,
                                               u16* __restrict__ out) {
  __shared__ u16 Kl[64 * 64];
  __shared__ u16 Vt[64 * 64];
  __shared__ u16 Pl[8][16 * 64];
  int swz = xcd_swz(blockIdx.x, gridDim.x);
  int p = swz & 1, h = (swz >> 1) & 7, b = swz >> 4;
  int qtA = p, qtB = 3 - p;
  int t = threadIdx.x;
  int w = t >> 6, lane = t & 63;
  int c = lane & 15, g = lane >> 4;

  auto loadQ = [&](int qt, bf16x8* qa) {
    int n = qt * 128 + w * 16 + c;
    const u16* qptr = qkv + (size_t)(b * N_ + n) * QKV_ + h * HD_ + g * 8;
    union { bf16x8 v; u16 s[8]; } a0, a1, r0, r1;
    a0.v = *(const bf16x8*)qptr;
    a1.v = *(const bf16x8*)(qptr + 32);
    const float2* tb = tab + n * 32 + g * 8;
#pragma unroll
    for (int j = 0; j < 8; ++j) {
      float2 cs = tb[j];
      float lo = b2f(a0.s[j]), hi = b2f(a1.s[j]);
      r0.s[j] = f2b((lo * cs.x - hi * cs.y) * SCALE_);
      r1.s[j] = f2b((hi * cs.x + lo * cs.y) * SCALE_);
    }
    qa[0] = r0.v;
    qa[1] = r1.v;
  };

  bf16x8 qaA[2], qaB[2];
  loadQ(qtA, qaA);
  loadQ(qtB, qaB);

  f32x4 OA[4] = {}, OB[4] = {};
  float mA[4], lA[4], mB[4], lB[4];
#pragma unroll
  for (int r = 0; r < 4; ++r) { mA[r] = mB[r] = -1e30f; lA[r] = lB[r] = 0.f; }

  int myA = 2 * qtA + (w >> 2), myB = 2 * qtB + (w >> 2);
  int ktmax = 2 * qtB + 1;

  union { bf16x8 v; u16 s[8]; } rk0, rk1;
  ushort4 rv0a, rv0b, rv1a, rv1b;
  int krow = t >> 2, ki0 = (t & 3) * 8;
  int tt = t - 256, vkp = (tt >> 3) * 2, vd0 = (tt & 7) * 8;

  auto loadT = [&](int kt) {
    if (t < 256) {
      const u16* base = qkv + (size_t)(b * N_ + kt * 64 + krow) * QKV_ + D_ + h * HD_;
      rk0.v = *(const bf16x8*)(base + ki0);
      rk1.v = *(const bf16x8*)(base + ki0 + 32);
    } else {
      const u16* v0p = qkv + (size_t)(b * N_ + kt * 64 + vkp) * QKV_ + 2 * D_ + h * HD_ + vd0;
      const u16* v1p = v0p + QKV_;
      rv0a = *(const ushort4*)v0p;
      rv0b = *(const ushort4*)(v0p + 4);
      rv1a = *(const ushort4*)v1p;
      rv1b = *(const ushort4*)(v1p + 4);
    }
  };

  auto writeT = [&](int kt) {
    if (t < 256) {
      int n = kt * 64 + krow;
      const float2* tb = tab + n * 32 + ki0;
      union { bf16x8 v; u16 s[8]; } olo, ohi;
#pragma unroll
      for (int j = 0; j < 8; ++j) {
        float2 cs = tb[j];
        float fl = b2f(rk0.s[j]), fh = b2f(rk1.s[j]);
        olo.s[j] = f2b(fl * cs.x - fh * cs.y);
        ohi.s[j] = f2b(fh * cs.x + fl * cs.y);
      }
      int bb = krow * 128 + ki0 * 2, sw = (krow & 7) << 4;
      *(bf16x8*)((char*)Kl + (bb ^ sw)) = olo.v;
      *(bf16x8*)((char*)Kl + ((bb + 64) ^ sw)) = ohi.v;
    } else {
      u16 a0[8] = {rv0a.x, rv0a.y, rv0a.z, rv0a.w, rv0b.x, rv0b.y, rv0b.z, rv0b.w};
      u16 a1[8] = {rv1a.x, rv1a.y, rv1a.z, rv1a.w, rv1b.x, rv1b.y, rv1b.z, rv1b.w};
      u32* VtW = (u32*)Vt;
#pragma unroll
      for (int j = 0; j < 8; ++j) {
        int d = vd0 + j;
        VtW[(d * 32 + (vkp >> 1)) ^ ((d & 7) << 2)] = ((u32)a1[j] << 16) | (u32)a0[j];
      }
    }
  };

  auto compute = [&](const bf16x8* qa, f32x4* O, float* m_r, float* l_r,
                     int myblk, int qt, int kt) {
    f32x4 s[4] = {};
#pragma unroll
    for (int ks = 0; ks < 2; ++ks) {
#pragma unroll
      for (int nt = 0; nt < 4; ++nt) {
        int kr = nt * 16 + c;
        int byteoff = (kr * 128 + (g * 8 + ks * 32) * 2) ^ ((kr & 7) << 4);
        bf16x8 kb = *(const bf16x8*)((const char*)Kl + byteoff);
        s[nt] = __builtin_amdgcn_mfma_f32_16x16x32_bf16(qa[ks], kb, s[nt], 0, 0, 0);
      }
    }
    if (kt == myblk) {
#pragma unroll
      for (int nt = 0; nt < 4; ++nt)
#pragma unroll
        for (int r = 0; r < 4; ++r)
          if (kt * 64 + nt * 16 + c > qt * 128 + w * 16 + g * 4 + r) s[nt][r] = -1e30f;
    }
    float tm[4], tl[4], fac[4];
#pragma unroll
    for (int r = 0; r < 4; ++r)
      tm[r] = fmaxf(fmaxf(s[0][r], s[1][r]), fmaxf(s[2][r], s[3][r]));
#pragma unroll
    for (int msk = 1; msk <= 8; msk <<= 1)
#pragma unroll
      for (int r = 0; r < 4; ++r)
        tm[r] = fmaxf(tm[r], __shfl_xor(tm[r], msk));
#pragma unroll
    for (int r = 0; r < 4; ++r) {
      float mn = fmaxf(m_r[r], tm[r]);
      fac[r] = __expf(m_r[r] - mn);
      m_r[r] = mn;
      tl[r] = 0.f;
    }
    u16* plw = Pl[w];
#pragma unroll
    for (int nt = 0; nt < 4; ++nt) {
#pragma unroll
      for (int r = 0; r < 4; ++r) {
        float pv = __expf(s[nt][r] - m_r[r]);
        tl[r] += pv;
        int q = g * 4 + r, kk = nt * 16 + c;
        plw[(q * 64 + kk) ^ ((q & 7) << 3)] = f2b(pv);
      }
    }
#pragma unroll
    for (int msk = 1; msk <= 8; msk <<= 1)
#pragma unroll
      for (int r = 0; r < 4; ++r) tl[r] += __shfl_xor(tl[r], msk);
#pragma unroll
    for (int r = 0; r < 4; ++r) l_r[r] = l_r[r] * fac[r] + tl[r];
#pragma unroll
    for (int nt = 0; nt < 4; ++nt)
#pragma unroll
      for (int r = 0; r < 4; ++r) O[nt][r] *= fac[r];
#pragma unroll
    for (int ks = 0; ks < 2; ++ks) {
      int pbyte = (c * 128 + (g * 8 + ks * 32) * 2) ^ ((c & 7) << 4);
      bf16x8 pa = *(const bf16x8*)((const char*)plw + pbyte);
#pragma unroll
      for (int nt = 0; nt < 4; ++nt) {
        int d = nt * 16 + c;
        int vbyte = (d * 128 + (g * 8 + ks * 32) * 2) ^ ((d & 7) << 4);
        bf16x8 vb = *(const bf16x8*)((const char*)Vt + vbyte);
        O[nt] = __builtin_amdgcn_mfma_f32_16x16x32_bf16(pa, vb, O[nt], 0, 0, 0);
      }
    }
  };

  loadT(0);
  for (int kt = 0; kt <= ktmax; ++kt) {
    writeT(kt);
    __syncthreads();
    if (kt < ktmax) loadT(kt + 1);
    if (kt <= myA) compute(qaA, OA, mA, lA, myA, qtA, kt);
    if (kt <= myB) compute(qaB, OB, mB, lB, myB, qtB, kt);
    __syncthreads();
  }

  auto store = [&](int qt, const f32x4* O, const float* l_r) {
    u16* dst = out + (size_t)(b * N_ + qt * 128 + w * 16) * D_ + h * HD_;
#pragma unroll
    for (int nt = 0; nt < 4; ++nt) {
#pragma unroll
      for (int r = 0; r < 4; ++r) {
        int q = g * 4 + r;
        dst[(size_t)q * D_ + nt * 16 + c] = f2b(O[nt][r] / l_r[r]);
      }
    }
  };
  store(qtA, OA, lA);
  store(qtB, OB, lB);
}

// ---------------- fused state path: LN -> sqkv -> 8-head attn -> w_so -> gate ----------------
// grid B_ (one block per batch), 256 threads.
__global__ __launch_bounds__(256) void k_state(
    const float* __restrict__ state, const float* __restrict__ g_ln,
    const float* __restrict__ b_ln, const float* __restrict__ w_sqkv,
    const float* __restrict__ w_so, const float* __restrict__ beta,
    const u16* __restrict__ qkv, const float2* __restrict__ tab,
    float* __restrict__ out2) {
  int b = blockIdx.x;
  int t = threadIdx.x;
  __shared__ float sln[512];
  __shared__ float sq[1536];
  __shared__ float sc[8][513];
  __shared__ float souts[512];
  __shared__ float wrs[4], wrq[4];

  // ---- LN of state row b ----
  float v0 = state[b * D_ + 2 * t], v1 = state[b * D_ + 2 * t + 1];
  float s = v0 + v1, q = v0 * v0 + v1 * v1;
#pragma unroll
  for (int o = 32; o >= 1; o >>= 1) { s += __shfl_xor(s, o); q += __shfl_xor(q, o); }
  int w = t >> 6, lane = t & 63;
  if (lane == 0) { wrs[w] = s; wrq[w] = q; }
  __syncthreads();
  s = wrs[0] + wrs[1] + wrs[2] + wrs[3];
  q = wrq[0] + wrq[1] + wrq[2] + wrq[3];
  float mean = s * (1.0f / D_);
  float var = q * (1.0f / D_) - mean * mean;
  float rstd = rsqrtf(var + 1e-5f);
  sln[2 * t] = (v0 - mean) * rstd * g_ln[2 * t] + b_ln[2 * t];
  sln[2 * t + 1] = (v1 - mean) * rstd * g_ln[2 * t + 1] + b_ln[2 * t + 1];
  __syncthreads();

  // ---- sqkv = sln @ w_sqkv (512 x 1536), coalesced per-d row broadcast ----
  {
    float acc[6] = {};
#pragma unroll 4
    for (int d = 0; d < 512; ++d) {
      float sv = sln[d];
      const float* wr = w_sqkv + (size_t)d * QKV_ + t;
#pragma unroll
      for (int p = 0; p < 6; ++p) acc[p] += sv * wr[p * 256];
    }
#pragma unroll
    for (int p = 0; p < 6; ++p) sq[p * 256 + t] = acc[p];
  }
  __syncthreads();

  // ---- attention: head h = t>>5, 32 lanes per head ----
  int h = t >> 5, li = t & 31;
  {
    const float* sqq = sq + h * HD_;
    for (int j = li; j < 513; j += 32) {
      float acc = 0.f;
      if (j == 0) {
        const float* kp = sq + D_ + h * HD_;
#pragma unroll
        for (int d = 0; d < HD_; ++d) acc += sqq[d] * kp[d];
      } else {
        const u16* kp = qkv + (size_t)(b * N_ + j - 1) * QKV_ + D_ + h * HD_;
        const float2* tb = tab + (size_t)(j - 1) * 32;
#pragma unroll
        for (int d = 0; d < 32; ++d) {
          float2 cs = tb[d];
          float klo = b2f(kp[d]), khi = b2f(kp[d + 32]);
          acc += sqq[d] * (klo * cs.x - khi * cs.y) + sqq[d + 32] * (khi * cs.x + klo * cs.y);
        }
      }
      sc[h][j] = acc * SCALE_;
    }
  }
  // per-head softmax over own strided elements, reduce within 32-lane group
  float m = -1e30f;
  for (int j = li; j < 513; j += 32) m = fmaxf(m, sc[h][j]);
#pragma unroll
  for (int o = 16; o >= 1; o >>= 1) m = fmaxf(m, __shfl_xor(m, o));
  float sum = 0.f;
  for (int j = li; j < 513; j += 32) {
    float p = __expf(sc[h][j] - m);
    sc[h][j] = p;
    sum += p;
  }
#pragma unroll
  for (int o = 16; o >= 1; o >>= 1) sum += __shfl_xor(sum, o);
  float inv = __builtin_amdgcn_rcpf(sum);
  __syncthreads();
  // ---- PV: each lane owns 2 d's ----
  {
    int d0 = li * 2;
    const float* svp = sq + 2 * D_ + h * HD_;
    float a0 = sc[h][0] * svp[d0];
    float a1 = sc[h][0] * svp[d0 + 1];
    for (int j = 1; j <= N_; ++j) {
      const u16* vp = qkv + (size_t)(b * N_ + j - 1) * QKV_ + 2 * D_ + h * HD_ + d0;
      float p = sc[h][j];
      a0 += p * b2f(vp[0]);
      a1 += p * b2f(vp[1]);
    }
    souts[h * HD_ + d0] = a0 * inv;
    souts[h * HD_ + d0 + 1] = a1 * inv;
  }
  __syncthreads();

  // ---- supd = souts @ w_so (512x512), gate, write ----
  {
    float acc0 = 0.f, acc1 = 0.f;
#pragma unroll 4
    for (int d = 0; d < 512; ++d) {
      float sv = souts[d];
      const float* wr = w_so + (size_t)d * D_ + t;
      acc0 += sv * wr[0];
      acc1 += sv * wr[256];
    }
    int c0 = t, c1 = t + 256;
    float g0 = __builtin_amdgcn_rcpf(1.0f + __expf(-beta[c0]));
    float g1 = __builtin_amdgcn_rcpf(1.0f + __expf(-beta[c1]));
    out2[b * D_ + c0] = state[b * D_ + c0] * g0 + acc0 * (1.0f - g0);
    out2[b * D_ + c1] = state[b * D_ + c1] * g1 + acc1 * (1.0f - g1);
  }
}

// ---------------- host launch ----------------
extern "C" void kernel_launch(void* const* d_in, const int* in_sizes, int n_in,
                              void* d_out, int out_size, void* d_ws, size_t ws_size,
                              hipStream_t stream) {
  (void)in_sizes; (void)n_in; (void)out_size; (void)ws_size;
  const int* ids = (const int*)d_in[0];
  const float* state = (const float*)d_in[1];
  const float* tok_emb = (const float*)d_in[2];
  const float* ln1_g = (const float*)d_in[3];
  const float* ln1_b = (const float*)d_in[4];
  const float* w_qkv = (const float*)d_in[5];
  const float* w_o = (const float*)d_in[6];
  const float* ln2_g = (const float*)d_in[7];
  const float* ln2_b = (const float*)d_in[8];
  const float* w_ff1 = (const float*)d_in[9];
  const float* b_ff1 = (const float*)d_in[10];
  const float* w_ff2 = (const float*)d_in[11];
  const float* b_ff2 = (const float*)d_in[12];
  const float* s_ln_g = (const float*)d_in[13];
  const float* s_ln_b = (const float*)d_in[14];
  const float* w_s_qkv = (const float*)d_in[15];
  const float* w_so = (const float*)d_in[16];
  const float* gate_beta = (const float*)d_in[17];
  // 18..21 dead: log_softmax over size-1 axis is exactly 0 -> output 0 all zeros.

  float* out0 = (float*)d_out;
  float* out1 = (float*)d_out + 16384;

  float* ws = (float*)d_ws;
  u16* x = (u16*)ws;                               // 16384x512 bf16
  u16* qkv_bf = (u16*)(ws + 8388608);              // 16384x1536 bf16 (aliases mid)
  u16* mid_bf = qkv_bf;                            // 16384x2048 bf16 (disjoint liveness)
  u16* h_bf = (u16*)(ws + 25165824);
  u16* ao_bf = (u16*)(ws + 29360128);
  u16* wq_t = (u16*)(ws + 33554432);               // 3 x 1536x512
  u16* wo_t = (u16*)(ws + 34734080);               // 2 x 512x512
  u16* wf1_t = (u16*)(ws + 34996224);              // 2 x 2048x512
  u16* wf2_t = (u16*)(ws + 36044800);              // 2 x 512x2048
  float2* tab = (float2*)(ws + 37191680);          // 512x32 float2

  const int M = B_ * N_;  // 16384

  k_prep<<<dim3(6976), dim3(256), 0, stream>>>(w_qkv, w_o, w_ff1, w_ff2,
                                               wq_t, wo_t, wf1_t, wf2_t, out0, tab);
  k_embed<<<dim3(M), dim3(128), 0, stream>>>(ids, tok_emb, x);

  for (int l = 0; l < 3; ++l) {
    k_ln<<<dim3(M / 4), dim3(256), 0, stream>>>(x, ln1_g + l * D_, ln1_b + l * D_, h_bf);
    if (l == 2) {
      // only K,V needed (n0 >= 512): 8 n-blocks with offset 4; rope applied in consumer
      k_mgemm<0, 1><<<dim3(8, 128), dim3(256), 0, stream>>>(
          h_bf, wq_t + (size_t)l * QKV_ * D_, nullptr, nullptr, qkv_bf, M, D_, QKV_, 4);
      break;
    }
    k_mgemm<0, 1><<<dim3(12, 128), dim3(256), 0, stream>>>(
        h_bf, wq_t + (size_t)l * QKV_ * D_, nullptr, nullptr, qkv_bf, M, D_, QKV_, 0);
    k_fattn<<<dim3(2 * H_ * B_), dim3(512), 0, stream>>>(qkv_bf, tab, ao_bf);
    k_mgemm<1, 1><<<dim3(4, 128), dim3(256), 0, stream>>>(
        ao_bf, wo_t + (size_t)l * D_ * D_, nullptr, x, x, M, D_, D_, 0);
    k_ln<<<dim3(M / 4), dim3(256), 0, stream>>>(x, ln2_g + l * D_, ln2_b + l * D_, h_bf);
    k_mgemm<2, 1><<<dim3(16, 128), dim3(256), 0, stream>>>(
        h_bf, wf1_t + (size_t)l * 4 * D_ * D_, b_ff1 + l * 4 * D_, nullptr, mid_bf, M, D_, 4 * D_, 0);
    k_mgemm<3, 1><<<dim3(4, 128), dim3(256), 0, stream>>>(
        mid_bf, wf2_t + (size_t)l * D_ * 4 * D_, b_ff2 + l * D_, x, x, M, 4 * D_, D_, 0);
  }

  // ---- fused state path at layer REC=2 ----
  k_state<<<dim3(B_), dim3(256), 0, stream>>>(state, s_ln_g, s_ln_b, w_s_qkv,
                                              w_so, gate_beta, qkv_bf, tab, out1);
}

// Round 14
// 612.644 us; speedup vs baseline: 1.1221x; 1.1221x over previous
//
#include <hip/hip_runtime.h>
#include <hip/hip_bf16.h>
#include <math.h>

#define B_ 32
#define N_ 512
#define D_ 512
#define H_ 8
#define HD_ 64
#define QKV_ 1536
#define SCALE_ 0.125f

typedef unsigned short u16;
typedef unsigned int u32;
typedef __attribute__((ext_vector_type(8))) short bf16x8;
typedef __attribute__((ext_vector_type(4))) float f32x4;

#define GLOBAL_AS __attribute__((address_space(1)))
#define LDS_AS __attribute__((address_space(3)))

// ---------------- utility ----------------
__device__ __forceinline__ float gelu_f(float x) {
  float u = 0.7978845608028654f * (x + 0.044715f * x * x * x);
  u = fminf(fmaxf(u, -15.f), 15.f);
  float e = __expf(2.f * u);
  float th = 1.f - 2.f * __builtin_amdgcn_rcpf(e + 1.f);
  return 0.5f * x * (1.0f + th);
}

__device__ __forceinline__ u16 f2b(float f) {
  union { float f; u32 u; } v;
  v.f = f;
  u32 r = (v.u + 0x7FFFu + ((v.u >> 16) & 1u)) >> 16;
  return (u16)r;
}

__device__ __forceinline__ float b2f(u16 x) {
  union { u32 u; float f; } v;
  v.u = ((u32)x) << 16;
  return v.f;
}

// XCD-chunked bijective swizzle (m204)
__device__ __forceinline__ int xcd_swz(int orig, int nwg) {
  int q = nwg >> 3, r = nwg & 7;
  int xcd = orig & 7, idx = orig >> 3;
  return (xcd < r ? xcd * (q + 1) : r * (q + 1) + (xcd - r) * q) + idx;
}

// ---------------- fused prep: zero out0 + rope table + all weight transposes ----------------
__global__ void k_prep(const float* __restrict__ w_qkv, const float* __restrict__ w_o,
                       const float* __restrict__ w_ff1, const float* __restrict__ w_ff2,
                       u16* __restrict__ wq_t, u16* __restrict__ wo_t,
                       u16* __restrict__ wf1_t, u16* __restrict__ wf2_t,
                       float* __restrict__ out0, float2* __restrict__ tab) {
  __shared__ float tile[32][33];
  int bid = blockIdx.x;
  int t = threadIdx.x;
  if (bid < 64) {
    int idx = bid * 256 + t;
    out0[idx] = 0.f;
    int n = idx >> 5, i = idx & 31;
    float inv = powf(10000.0f, -(float)i * (1.0f / 32.0f));
    float f = (float)n * inv;
    float s, c;
    sincosf(f, &s, &c);
    tab[idx] = make_float2(c, s);
    return;
  }
  int b2 = bid - 64;
  const float* W;
  u16* Wt;
  int K, N;
  if (b2 < 2304) {
    int l = b2 / 768; b2 -= l * 768;
    W = w_qkv + (size_t)l * D_ * QKV_; Wt = wq_t + (size_t)l * QKV_ * D_;
    K = D_; N = QKV_;
  } else if (b2 < 2816) {
    b2 -= 2304; int l = b2 >> 8; b2 &= 255;
    W = w_o + (size_t)l * D_ * D_; Wt = wo_t + (size_t)l * D_ * D_;
    K = D_; N = D_;
  } else if (b2 < 4864) {
    b2 -= 2816; int l = b2 >> 10; b2 &= 1023;
    W = w_ff1 + (size_t)l * D_ * 4 * D_; Wt = wf1_t + (size_t)l * 4 * D_ * D_;
    K = D_; N = 4 * D_;
  } else {
    b2 -= 4864; int l = b2 >> 10; b2 &= 1023;
    W = w_ff2 + (size_t)l * 4 * D_ * D_; Wt = wf2_t + (size_t)l * D_ * 4 * D_;
    K = 4 * D_; N = D_;
  }
  int nbx = N >> 5;
  int bx = b2 % nbx, by = b2 / nbx;
  int k0 = by * 32, n0 = bx * 32;
  int r = t >> 3, c4 = (t & 7) * 4;
  float4 v = *(const float4*)&W[(size_t)(k0 + r) * N + n0 + c4];
  tile[r][c4] = v.x; tile[r][c4 + 1] = v.y; tile[r][c4 + 2] = v.z; tile[r][c4 + 3] = v.w;
  __syncthreads();
  ushort4 o;
  o.x = f2b(tile[c4 + 0][r]); o.y = f2b(tile[c4 + 1][r]);
  o.z = f2b(tile[c4 + 2][r]); o.w = f2b(tile[c4 + 3][r]);
  *(ushort4*)&Wt[(size_t)(n0 + r) * K + k0 + c4] = o;
}

// ---------------- embedding gather -> bf16 x ----------------
__global__ void k_embed(const int* __restrict__ ids, const float* __restrict__ emb,
                        u16* __restrict__ x) {
  int row = blockIdx.x;
  int id = ids[row];
  float4 v = ((const float4*)(emb + (size_t)id * D_))[threadIdx.x];
  ushort4 o;
  o.x = f2b(v.x); o.y = f2b(v.y); o.z = f2b(v.z); o.w = f2b(v.w);
  ((ushort4*)(x + (size_t)row * D_))[threadIdx.x] = o;
}

// ---------------- row LayerNorm over D=512, bf16 in/out, 4 rows/block ----------------
__global__ void k_ln(const u16* __restrict__ in, const float* __restrict__ gw,
                     const float* __restrict__ bw, u16* __restrict__ out) {
  int row = blockIdx.x * 4 + (threadIdx.x >> 6);
  int lane = threadIdx.x & 63;
  union { bf16x8 v; u16 s[8]; } u;
  u.v = *(const bf16x8*)(in + (size_t)row * D_ + lane * 8);
  float f[8];
#pragma unroll
  for (int j = 0; j < 8; ++j) f[j] = b2f(u.s[j]);
  float s = 0.f, q = 0.f;
#pragma unroll
  for (int j = 0; j < 8; ++j) { s += f[j]; q += f[j] * f[j]; }
#pragma unroll
  for (int o = 32; o >= 1; o >>= 1) {
    s += __shfl_xor(s, o);
    q += __shfl_xor(q, o);
  }
  float mean = s * (1.0f / D_);
  float var = q * (1.0f / D_) - mean * mean;
  float rstd = rsqrtf(var + 1e-5f);
  float4 g0 = *(const float4*)(gw + lane * 8);
  float4 g1 = *(const float4*)(gw + lane * 8 + 4);
  float4 b0 = *(const float4*)(bw + lane * 8);
  float4 b1 = *(const float4*)(bw + lane * 8 + 4);
  float gg[8] = {g0.x, g0.y, g0.z, g0.w, g1.x, g1.y, g1.z, g1.w};
  float bb[8] = {b0.x, b0.y, b0.z, b0.w, b1.x, b1.y, b1.z, b1.w};
  union { bf16x8 v; u16 s[8]; } ov;
#pragma unroll
  for (int j = 0; j < 8; ++j) ov.s[j] = f2b((f[j] - mean) * rstd * gg[j] + bb[j]);
  *(bf16x8*)(out + (size_t)row * D_ + lane * 8) = ov.v;
}

// ---------------- fp32 row LayerNorm (state rows), 4 rows/block ----------------
__global__ void k_lnf(const float* __restrict__ in, const float* __restrict__ gw,
                      const float* __restrict__ bw, float* __restrict__ out) {
  int row = blockIdx.x * 4 + (threadIdx.x >> 6);
  int lane = threadIdx.x & 63;
  const float* p = in + (size_t)row * D_ + lane * 8;
  float4 v0 = *(const float4*)p;
  float4 v1 = *(const float4*)(p + 4);
  float s = v0.x + v0.y + v0.z + v0.w + v1.x + v1.y + v1.z + v1.w;
  float q = v0.x * v0.x + v0.y * v0.y + v0.z * v0.z + v0.w * v0.w +
            v1.x * v1.x + v1.y * v1.y + v1.z * v1.z + v1.w * v1.w;
#pragma unroll
  for (int o = 32; o >= 1; o >>= 1) {
    s += __shfl_xor(s, o);
    q += __shfl_xor(q, o);
  }
  float mean = s * (1.0f / D_);
  float var = q * (1.0f / D_) - mean * mean;
  float rstd = rsqrtf(var + 1e-5f);
  float4 g0 = *(const float4*)(gw + lane * 8);
  float4 g1 = *(const float4*)(gw + lane * 8 + 4);
  float4 b0 = *(const float4*)(bw + lane * 8);
  float4 b1 = *(const float4*)(bw + lane * 8 + 4);
  float* op = out + (size_t)row * D_ + lane * 8;
  *(float4*)op = make_float4((v0.x - mean) * rstd * g0.x + b0.x,
                             (v0.y - mean) * rstd * g0.y + b0.y,
                             (v0.z - mean) * rstd * g0.z + b0.z,
                             (v0.w - mean) * rstd * g0.w + b0.w);
  *(float4*)(op + 4) = make_float4((v1.x - mean) * rstd * g1.x + b1.x,
                                   (v1.y - mean) * rstd * g1.y + b1.y,
                                   (v1.z - mean) * rstd * g1.z + b1.z,
                                   (v1.w - mean) * rstd * g1.w + b1.w);
}

// ---------------- bf16 MFMA GEMM: 128x128, BK=64 (two 32-sub-tiles), dbuf ----------------
template <int EPI, int BF16OUT>
__global__ __launch_bounds__(256) void k_mgemm(
    const u16* __restrict__ A, const u16* __restrict__ Bt,
    const float* __restrict__ bias, const u16* __restrict__ resid,
    void* __restrict__ Cv, int M, int K, int Nc, int nb0) {
  __shared__ u16 As[2][2][128 * 32];
  __shared__ u16 Bs[2][2][128 * 32];
  int t = threadIdx.x;
  int wave = t >> 6, lane = t & 63;
  int nwg = gridDim.x * gridDim.y;
  int swz = xcd_swz(blockIdx.y * gridDim.x + blockIdx.x, nwg);
  int m0 = (swz / gridDim.x) * 128;
  int n0 = ((swz % gridDim.x) + nb0) * 128;
  int wr = wave >> 1, wc = wave & 1;
  f32x4 acc[4][4] = {};

  int srow = lane >> 2;
  int scol = ((lane & 3) ^ ((lane >> 3) & 3)) * 8;
  const u16* gaBase = A + (size_t)(m0 + wave * 32 + srow) * K + scol;
  const u16* gbBase = Bt + (size_t)(n0 + wave * 32 + srow) * K + scol;

#define STAGE_MG(bsel, sub, kk)                                                \
  {                                                                            \
    _Pragma("unroll") for (int i_ = 0; i_ < 2; ++i_) {                         \
      int rbase_ = wave * 32 + i_ * 16;                                        \
      __builtin_amdgcn_global_load_lds(                                        \
          (const GLOBAL_AS void*)(gaBase + (size_t)(i_ * 16) * K + (kk)),      \
          (LDS_AS void*)&As[bsel][sub][rbase_ * 32], 16, 0, 0);                \
      __builtin_amdgcn_global_load_lds(                                        \
          (const GLOBAL_AS void*)(gbBase + (size_t)(i_ * 16) * K + (kk)),      \
          (LDS_AS void*)&Bs[bsel][sub][rbase_ * 32], 16, 0, 0);                \
    }                                                                          \
  }

  int c = lane & 15, g = lane >> 4;
  int chread = (g ^ ((c >> 1) & 3)) * 8;

  int nIter = K >> 6;
  STAGE_MG(0, 0, 0);
  STAGE_MG(0, 1, 32);
  __syncthreads();
  for (int it = 0; it < nIter; ++it) {
    int cur = it & 1;
    if (it + 1 < nIter) {
      STAGE_MG(cur ^ 1, 0, (size_t)(it + 1) * 64);
      STAGE_MG(cur ^ 1, 1, (size_t)(it + 1) * 64 + 32);
    }
#pragma unroll
    for (int sub = 0; sub < 2; ++sub) {
      const u16* as = As[cur][sub];
      const u16* bs = Bs[cur][sub];
      bf16x8 af[4], bfr[4];
#pragma unroll
      for (int mi = 0; mi < 4; ++mi)
        af[mi] = *(const bf16x8*)&as[(wr * 64 + mi * 16 + c) * 32 + chread];
#pragma unroll
      for (int ni = 0; ni < 4; ++ni)
        bfr[ni] = *(const bf16x8*)&bs[(wc * 64 + ni * 16 + c) * 32 + chread];
#pragma unroll
      for (int mi = 0; mi < 4; ++mi)
#pragma unroll
        for (int ni = 0; ni < 4; ++ni)
          acc[mi][ni] = __builtin_amdgcn_mfma_f32_16x16x32_bf16(bfr[ni], af[mi], acc[mi][ni], 0, 0, 0);
    }
    __syncthreads();
  }
#undef STAGE_MG

#pragma unroll
  for (int mi = 0; mi < 4; ++mi) {
    int m = m0 + wr * 64 + mi * 16 + (lane & 15);
    size_t rowoff = (size_t)m * Nc;
#pragma unroll
    for (int ni = 0; ni < 4; ++ni) {
      int n = n0 + wc * 64 + ni * 16 + (lane >> 4) * 4;
      float v0 = acc[mi][ni][0], v1 = acc[mi][ni][1],
            v2 = acc[mi][ni][2], v3 = acc[mi][ni][3];
      if (EPI == 2 || EPI == 3) {
        float4 bb = *(const float4*)&bias[n];
        v0 += bb.x; v1 += bb.y; v2 += bb.z; v3 += bb.w;
      }
      if (EPI == 2) {
        v0 = gelu_f(v0); v1 = gelu_f(v1); v2 = gelu_f(v2); v3 = gelu_f(v3);
      }
      if (EPI == 1 || EPI == 3) {
        ushort4 rr = *(const ushort4*)&resid[rowoff + n];
        v0 += b2f(rr.x); v1 += b2f(rr.y); v2 += b2f(rr.z); v3 += b2f(rr.w);
      }
      if (BF16OUT) {
        ushort4 o;
        o.x = f2b(v0); o.y = f2b(v1); o.z = f2b(v2); o.w = f2b(v3);
        *(ushort4*)&((u16*)Cv)[rowoff + n] = o;
      } else {
        *(float4*)&((float*)Cv)[rowoff + n] = make_float4(v0, v1, v2, v3);
      }
    }
  }
}

// ---------------- fp32 tiled GEMM (state path, tiny M) ----------------
template <int EPI>
__global__ __launch_bounds__(256) void k_gemm(const float* __restrict__ A,
                                              const float* __restrict__ W,
                                              const float* __restrict__ bias,
                                              const float* __restrict__ resid,
                                              float* __restrict__ C,
                                              int M, int K, int Nc) {
  __shared__ float As[32][68];
  __shared__ float Bs[32][68];
  int t = threadIdx.x;
  int tx = t & 15, ty = t >> 4;
  int m0 = blockIdx.y * 64, n0 = blockIdx.x * 64;
  float acc[4][4] = {};
  int ar = t >> 2, akc = (t & 3) * 8;
  int bkr = t >> 3, bnc = (t & 7) * 8;
  int garow = m0 + ar;
  bool aval = garow < M;
  const float* Aptr = A + (size_t)(aval ? garow : 0) * K + akc;
  const float* Wptr = W + (size_t)bkr * Nc + n0 + bnc;

  for (int k0 = 0; k0 < K; k0 += 32) {
    float4 a0, a1;
    if (aval) {
      a0 = *(const float4*)(Aptr + k0);
      a1 = *(const float4*)(Aptr + k0 + 4);
    } else {
      a0 = make_float4(0.f, 0.f, 0.f, 0.f);
      a1 = a0;
    }
    As[akc + 0][ar] = a0.x; As[akc + 1][ar] = a0.y;
    As[akc + 2][ar] = a0.z; As[akc + 3][ar] = a0.w;
    As[akc + 4][ar] = a1.x; As[akc + 5][ar] = a1.y;
    As[akc + 6][ar] = a1.z; As[akc + 7][ar] = a1.w;
    float4 b0 = *(const float4*)(Wptr + (size_t)k0 * Nc);
    float4 b1 = *(const float4*)(Wptr + (size_t)k0 * Nc + 4);
    *(float4*)&Bs[bkr][bnc] = b0;
    *(float4*)&Bs[bkr][bnc + 4] = b1;
    __syncthreads();
#pragma unroll
    for (int k = 0; k < 32; ++k) {
      float4 av = *(float4*)&As[k][ty * 4];
      float4 bv = *(float4*)&Bs[k][tx * 4];
      float a[4] = {av.x, av.y, av.z, av.w};
      float b[4] = {bv.x, bv.y, bv.z, bv.w};
#pragma unroll
      for (int i = 0; i < 4; ++i)
#pragma unroll
        for (int j = 0; j < 4; ++j) acc[i][j] += a[i] * b[j];
    }
    __syncthreads();
  }
#pragma unroll
  for (int i = 0; i < 4; ++i) {
    int m = m0 + ty * 4 + i;
    if (m >= M) break;
    size_t off = (size_t)m * Nc + n0 + tx * 4;
    float r[4];
#pragma unroll
    for (int j = 0; j < 4; ++j) {
      float v = acc[i][j];
      if (EPI == 2 || EPI == 3) v += bias[n0 + tx * 4 + j];
      if (EPI == 2) v = gelu_f(v);
      if (EPI == 1 || EPI == 3) v += resid[off + j];
      r[j] = v;
    }
    *(float4*)&C[off] = make_float4(r[0], r[1], r[2], r[3]);
  }
}

// ---------------- MFMA flash attention: paired q-tiles + async stage ----------------
__global__ __launch_bounds__(512) void k_fattn(const u16* __restrict__ qkv,
                                               const float2* __restrict__ tab,
                                               u16* __restrict__ out) {
  __shared__ u16 Kl[64 * 64];
  __shared__ u16 Vt[64 * 64];
  __shared__ u16 Pl[8][16 * 64];
  int swz = xcd_swz(blockIdx.x, gridDim.x);
  int p = swz & 1, h = (swz >> 1) & 7, b = swz >> 4;
  int qtA = p, qtB = 3 - p;
  int t = threadIdx.x;
  int w = t >> 6, lane = t & 63;
  int c = lane & 15, g = lane >> 4;

  auto loadQ = [&](int qt, bf16x8* qa) {
    int n = qt * 128 + w * 16 + c;
    const u16* qptr = qkv + (size_t)(b * N_ + n) * QKV_ + h * HD_ + g * 8;
    union { bf16x8 v; u16 s[8]; } a0, a1, r0, r1;
    a0.v = *(const bf16x8*)qptr;
    a1.v = *(const bf16x8*)(qptr + 32);
    const float2* tb = tab + n * 32 + g * 8;
#pragma unroll
    for (int j = 0; j < 8; ++j) {
      float2 cs = tb[j];
      float lo = b2f(a0.s[j]), hi = b2f(a1.s[j]);
      r0.s[j] = f2b((lo * cs.x - hi * cs.y) * SCALE_);
      r1.s[j] = f2b((hi * cs.x + lo * cs.y) * SCALE_);
    }
    qa[0] = r0.v;
    qa[1] = r1.v;
  };

  bf16x8 qaA[2], qaB[2];
  loadQ(qtA, qaA);
  loadQ(qtB, qaB);

  f32x4 OA[4] = {}, OB[4] = {};
  float mA[4], lA[4], mB[4], lB[4];
#pragma unroll
  for (int r = 0; r < 4; ++r) { mA[r] = mB[r] = -1e30f; lA[r] = lB[r] = 0.f; }

  int myA = 2 * qtA + (w >> 2), myB = 2 * qtB + (w >> 2);
  int ktmax = 2 * qtB + 1;

  union { bf16x8 v; u16 s[8]; } rk0, rk1;
  ushort4 rv0a, rv0b, rv1a, rv1b;
  int krow = t >> 2, ki0 = (t & 3) * 8;
  int tt = t - 256, vkp = (tt >> 3) * 2, vd0 = (tt & 7) * 8;

  auto loadT = [&](int kt) {
    if (t < 256) {
      const u16* base = qkv + (size_t)(b * N_ + kt * 64 + krow) * QKV_ + D_ + h * HD_;
      rk0.v = *(const bf16x8*)(base + ki0);
      rk1.v = *(const bf16x8*)(base + ki0 + 32);
    } else {
      const u16* v0p = qkv + (size_t)(b * N_ + kt * 64 + vkp) * QKV_ + 2 * D_ + h * HD_ + vd0;
      const u16* v1p = v0p + QKV_;
      rv0a = *(const ushort4*)v0p;
      rv0b = *(const ushort4*)(v0p + 4);
      rv1a = *(const ushort4*)v1p;
      rv1b = *(const ushort4*)(v1p + 4);
    }
  };

  auto writeT = [&](int kt) {
    if (t < 256) {
      int n = kt * 64 + krow;
      const float2* tb = tab + n * 32 + ki0;
      union { bf16x8 v; u16 s[8]; } olo, ohi;
#pragma unroll
      for (int j = 0; j < 8; ++j) {
        float2 cs = tb[j];
        float fl = b2f(rk0.s[j]), fh = b2f(rk1.s[j]);
        olo.s[j] = f2b(fl * cs.x - fh * cs.y);
        ohi.s[j] = f2b(fh * cs.x + fl * cs.y);
      }
      int bb = krow * 128 + ki0 * 2, sw = (krow & 7) << 4;
      *(bf16x8*)((char*)Kl + (bb ^ sw)) = olo.v;
      *(bf16x8*)((char*)Kl + ((bb + 64) ^ sw)) = ohi.v;
    } else {
      u16 a0[8] = {rv0a.x, rv0a.y, rv0a.z, rv0a.w, rv0b.x, rv0b.y, rv0b.z, rv0b.w};
      u16 a1[8] = {rv1a.x, rv1a.y, rv1a.z, rv1a.w, rv1b.x, rv1b.y, rv1b.z, rv1b.w};
      u32* VtW = (u32*)Vt;
#pragma unroll
      for (int j = 0; j < 8; ++j) {
        int d = vd0 + j;
        VtW[(d * 32 + (vkp >> 1)) ^ ((d & 7) << 2)] = ((u32)a1[j] << 16) | (u32)a0[j];
      }
    }
  };

  auto compute = [&](const bf16x8* qa, f32x4* O, float* m_r, float* l_r,
                     int myblk, int qt, int kt) {
    f32x4 s[4] = {};
#pragma unroll
    for (int ks = 0; ks < 2; ++ks) {
#pragma unroll
      for (int nt = 0; nt < 4; ++nt) {
        int kr = nt * 16 + c;
        int byteoff = (kr * 128 + (g * 8 + ks * 32) * 2) ^ ((kr & 7) << 4);
        bf16x8 kb = *(const bf16x8*)((const char*)Kl + byteoff);
        s[nt] = __builtin_amdgcn_mfma_f32_16x16x32_bf16(qa[ks], kb, s[nt], 0, 0, 0);
      }
    }
    if (kt == myblk) {
#pragma unroll
      for (int nt = 0; nt < 4; ++nt)
#pragma unroll
        for (int r = 0; r < 4; ++r)
          if (kt * 64 + nt * 16 + c > qt * 128 + w * 16 + g * 4 + r) s[nt][r] = -1e30f;
    }
    float tm[4], tl[4], fac[4];
#pragma unroll
    for (int r = 0; r < 4; ++r)
      tm[r] = fmaxf(fmaxf(s[0][r], s[1][r]), fmaxf(s[2][r], s[3][r]));
#pragma unroll
    for (int msk = 1; msk <= 8; msk <<= 1)
#pragma unroll
      for (int r = 0; r < 4; ++r)
        tm[r] = fmaxf(tm[r], __shfl_xor(tm[r], msk));
#pragma unroll
    for (int r = 0; r < 4; ++r) {
      float mn = fmaxf(m_r[r], tm[r]);
      fac[r] = __expf(m_r[r] - mn);
      m_r[r] = mn;
      tl[r] = 0.f;
    }
    u16* plw = Pl[w];
#pragma unroll
    for (int nt = 0; nt < 4; ++nt) {
#pragma unroll
      for (int r = 0; r < 4; ++r) {
        float pv = __expf(s[nt][r] - m_r[r]);
        tl[r] += pv;
        int q = g * 4 + r, kk = nt * 16 + c;
        plw[(q * 64 + kk) ^ ((q & 7) << 3)] = f2b(pv);
      }
    }
#pragma unroll
    for (int msk = 1; msk <= 8; msk <<= 1)
#pragma unroll
      for (int r = 0; r < 4; ++r) tl[r] += __shfl_xor(tl[r], msk);
#pragma unroll
    for (int r = 0; r < 4; ++r) l_r[r] = l_r[r] * fac[r] + tl[r];
#pragma unroll
    for (int nt = 0; nt < 4; ++nt)
#pragma unroll
      for (int r = 0; r < 4; ++r) O[nt][r] *= fac[r];
#pragma unroll
    for (int ks = 0; ks < 2; ++ks) {
      int pbyte = (c * 128 + (g * 8 + ks * 32) * 2) ^ ((c & 7) << 4);
      bf16x8 pa = *(const bf16x8*)((const char*)plw + pbyte);
#pragma unroll
      for (int nt = 0; nt < 4; ++nt) {
        int d = nt * 16 + c;
        int vbyte = (d * 128 + (g * 8 + ks * 32) * 2) ^ ((d & 7) << 4);
        bf16x8 vb = *(const bf16x8*)((const char*)Vt + vbyte);
        O[nt] = __builtin_amdgcn_mfma_f32_16x16x32_bf16(pa, vb, O[nt], 0, 0, 0);
      }
    }
  };

  loadT(0);
  for (int kt = 0; kt <= ktmax; ++kt) {
    writeT(kt);
    __syncthreads();
    if (kt < ktmax) loadT(kt + 1);
    if (kt <= myA) compute(qaA, OA, mA, lA, myA, qtA, kt);
    if (kt <= myB) compute(qaB, OB, mB, lB, myB, qtB, kt);
    __syncthreads();
  }

  auto store = [&](int qt, const f32x4* O, const float* l_r) {
    u16* dst = out + (size_t)(b * N_ + qt * 128 + w * 16) * D_ + h * HD_;
#pragma unroll
    for (int nt = 0; nt < 4; ++nt) {
#pragma unroll
      for (int r = 0; r < 4; ++r) {
        int q = g * 4 + r;
        dst[(size_t)q * D_ + nt * 16 + c] = f2b(O[nt][r] / l_r[r]);
      }
    }
  };
  store(qtA, OA, lA);
  store(qtB, OB, lB);
}

// ---------------- state attention: 1 query, 513 keys, per (b,h); rope k inline ----------------
__global__ __launch_bounds__(128) void k_state_attn(const float* __restrict__ sqkv,
                                                    const u16* __restrict__ qkv,
                                                    const float2* __restrict__ tab,
                                                    float* __restrict__ outs) {
  int h = blockIdx.x, b = blockIdx.y;
  __shared__ float sq[HD_];
  __shared__ float sc[513];
  __shared__ float red[128];
  int t = threadIdx.x;
  if (t < HD_) sq[t] = sqkv[(size_t)b * QKV_ + h * HD_ + t];
  __syncthreads();
  for (int j = t; j < 513; j += 128) {
    float acc = 0.f;
    if (j == 0) {
      const float* kp = sqkv + (size_t)b * QKV_ + D_ + h * HD_;
#pragma unroll
      for (int d = 0; d < HD_; ++d) acc += sq[d] * kp[d];
    } else {
      const u16* kp = qkv + (size_t)(b * N_ + j - 1) * QKV_ + D_ + h * HD_;
      const float2* tb = tab + (size_t)(j - 1) * 32;
#pragma unroll
      for (int d = 0; d < 32; ++d) {
        float2 cs = tb[d];
        float klo = b2f(kp[d]), khi = b2f(kp[d + 32]);
        acc += sq[d] * (klo * cs.x - khi * cs.y) + sq[d + 32] * (khi * cs.x + klo * cs.y);
      }
    }
    sc[j] = acc * SCALE_;
  }
  __syncthreads();
  float m = -1e30f;
  for (int j = t; j < 513; j += 128) m = fmaxf(m, sc[j]);
  red[t] = m;
  __syncthreads();
  for (int s = 64; s > 0; s >>= 1) {
    if (t < s) red[t] = fmaxf(red[t], red[t + s]);
    __syncthreads();
  }
  m = red[0];
  __syncthreads();
  float sum = 0.f;
  for (int j = t; j < 513; j += 128) {
    float p = expf(sc[j] - m);
    sc[j] = p;
    sum += p;
  }
  red[t] = sum;
  __syncthreads();
  for (int s = 64; s > 0; s >>= 1) {
    if (t < s) red[t] += red[t + s];
    __syncthreads();
  }
  float tot = red[0];
  if (t < HD_) {
    int d = t;
    float acc = sc[0] * sqkv[(size_t)b * QKV_ + 2 * D_ + h * HD_ + d];
    for (int j = 1; j <= N_; ++j)
      acc += sc[j] * b2f(qkv[(size_t)(b * N_ + j - 1) * QKV_ + 2 * D_ + h * HD_ + d]);
    outs[(size_t)b * D_ + h * HD_ + d] = acc / tot;
  }
}

// ---------------- gated state update ----------------
__global__ void k_gate(const float* __restrict__ state, const float* __restrict__ upd,
                       const float* __restrict__ beta, float* __restrict__ out2) {
  int idx = blockIdx.x * 256 + threadIdx.x;
  int c = idx & (D_ - 1);
  float g = __builtin_amdgcn_rcpf(1.0f + __expf(-beta[c]));
  out2[idx] = state[idx] * g + upd[idx] * (1.0f - g);
}

// ---------------- host launch ----------------
extern "C" void kernel_launch(void* const* d_in, const int* in_sizes, int n_in,
                              void* d_out, int out_size, void* d_ws, size_t ws_size,
                              hipStream_t stream) {
  (void)in_sizes; (void)n_in; (void)out_size; (void)ws_size;
  const int* ids = (const int*)d_in[0];
  const float* state = (const float*)d_in[1];
  const float* tok_emb = (const float*)d_in[2];
  const float* ln1_g = (const float*)d_in[3];
  const float* ln1_b = (const float*)d_in[4];
  const float* w_qkv = (const float*)d_in[5];
  const float* w_o = (const float*)d_in[6];
  const float* ln2_g = (const float*)d_in[7];
  const float* ln2_b = (const float*)d_in[8];
  const float* w_ff1 = (const float*)d_in[9];
  const float* b_ff1 = (const float*)d_in[10];
  const float* w_ff2 = (const float*)d_in[11];
  const float* b_ff2 = (const float*)d_in[12];
  const float* s_ln_g = (const float*)d_in[13];
  const float* s_ln_b = (const float*)d_in[14];
  const float* w_s_qkv = (const float*)d_in[15];
  const float* w_so = (const float*)d_in[16];
  const float* gate_beta = (const float*)d_in[17];
  // 18..21 dead: log_softmax over size-1 axis is exactly 0 -> output 0 all zeros.

  float* out0 = (float*)d_out;
  float* out1 = (float*)d_out + 16384;

  float* ws = (float*)d_ws;
  u16* x = (u16*)ws;                               // 16384x512 bf16
  u16* qkv_bf = (u16*)(ws + 8388608);              // 16384x1536 bf16 (aliases mid)
  u16* mid_bf = qkv_bf;                            // 16384x2048 bf16 (disjoint liveness)
  u16* h_bf = (u16*)(ws + 25165824);
  u16* ao_bf = (u16*)(ws + 29360128);
  u16* wq_t = (u16*)(ws + 33554432);               // 3 x 1536x512
  u16* wo_t = (u16*)(ws + 34734080);               // 2 x 512x512
  u16* wf1_t = (u16*)(ws + 34996224);              // 2 x 2048x512
  u16* wf2_t = (u16*)(ws + 36044800);              // 2 x 512x2048
  float2* tab = (float2*)(ws + 37191680);          // 512x32 float2 (32768 f)
  float* sln = ws + 37224448;
  float* sqkv = sln + 16384;
  float* souts = sqkv + 49152;
  float* supd = souts + 16384;

  const int M = B_ * N_;  // 16384

  k_prep<<<dim3(6976), dim3(256), 0, stream>>>(w_qkv, w_o, w_ff1, w_ff2,
                                               wq_t, wo_t, wf1_t, wf2_t, out0, tab);
  k_embed<<<dim3(M), dim3(128), 0, stream>>>(ids, tok_emb, x);

  for (int l = 0; l < 3; ++l) {
    k_ln<<<dim3(M / 4), dim3(256), 0, stream>>>(x, ln1_g + l * D_, ln1_b + l * D_, h_bf);
    if (l == 2) {
      // only K,V needed (n0 >= 512): 8 n-blocks with offset 4; rope applied in consumer
      k_mgemm<0, 1><<<dim3(8, 128), dim3(256), 0, stream>>>(
          h_bf, wq_t + (size_t)l * QKV_ * D_, nullptr, nullptr, qkv_bf, M, D_, QKV_, 4);
      break;
    }
    k_mgemm<0, 1><<<dim3(12, 128), dim3(256), 0, stream>>>(
        h_bf, wq_t + (size_t)l * QKV_ * D_, nullptr, nullptr, qkv_bf, M, D_, QKV_, 0);
    k_fattn<<<dim3(2 * H_ * B_), dim3(512), 0, stream>>>(qkv_bf, tab, ao_bf);
    k_mgemm<1, 1><<<dim3(4, 128), dim3(256), 0, stream>>>(
        ao_bf, wo_t + (size_t)l * D_ * D_, nullptr, x, x, M, D_, D_, 0);
    k_ln<<<dim3(M / 4), dim3(256), 0, stream>>>(x, ln2_g + l * D_, ln2_b + l * D_, h_bf);
    k_mgemm<2, 1><<<dim3(16, 128), dim3(256), 0, stream>>>(
        h_bf, wf1_t + (size_t)l * 4 * D_ * D_, b_ff1 + l * 4 * D_, nullptr, mid_bf, M, D_, 4 * D_, 0);
    k_mgemm<3, 1><<<dim3(4, 128), dim3(256), 0, stream>>>(
        mid_bf, wf2_t + (size_t)l * D_ * 4 * D_, b_ff2 + l * D_, x, x, M, 4 * D_, D_, 0);
  }

  // ---- state path at layer REC=2 (qkv_bf holds raw k,v of layer 2; rope inline) ----
  k_lnf<<<dim3(B_ / 4), dim3(256), 0, stream>>>(state, s_ln_g, s_ln_b, sln);
  k_gemm<0><<<dim3(24, 1), dim3(256), 0, stream>>>(
      sln, w_s_qkv, nullptr, nullptr, sqkv, B_, D_, QKV_);
  k_state_attn<<<dim3(H_, B_), dim3(128), 0, stream>>>(sqkv, qkv_bf, tab, souts);
  k_gemm<0><<<dim3(8, 1), dim3(256), 0, stream>>>(
      souts, w_so, nullptr, nullptr, supd, B_, D_, D_);
  k_gate<<<dim3(64), dim3(256), 0, stream>>>(state, supd, gate_beta, out1);
}

// Round 15
// 608.079 us; speedup vs baseline: 1.1305x; 1.0075x over previous
//
#include <hip/hip_runtime.h>
#include <hip/hip_bf16.h>
#include <math.h>

#define B_ 32
#define N_ 512
#define D_ 512
#define H_ 8
#define HD_ 64
#define QKV_ 1536
#define SCALE_ 0.125f

typedef unsigned short u16;
typedef unsigned int u32;
typedef __attribute__((ext_vector_type(8))) short bf16x8;
typedef __attribute__((ext_vector_type(4))) float f32x4;

#define GLOBAL_AS __attribute__((address_space(1)))
#define LDS_AS __attribute__((address_space(3)))

// ---------------- utility ----------------
__device__ __forceinline__ float gelu_f(float x) {
  float u = 0.7978845608028654f * (x + 0.044715f * x * x * x);
  u = fminf(fmaxf(u, -15.f), 15.f);
  float e = __expf(2.f * u);
  float th = 1.f - 2.f * __builtin_amdgcn_rcpf(e + 1.f);
  return 0.5f * x * (1.0f + th);
}

__device__ __forceinline__ u16 f2b(float f) {
  union { float f; u32 u; } v;
  v.f = f;
  u32 r = (v.u + 0x7FFFu + ((v.u >> 16) & 1u)) >> 16;
  return (u16)r;
}

__device__ __forceinline__ float b2f(u16 x) {
  union { u32 u; float f; } v;
  v.u = ((u32)x) << 16;
  return v.f;
}

// XCD-chunked bijective swizzle (m204)
__device__ __forceinline__ int xcd_swz(int orig, int nwg) {
  int q = nwg >> 3, r = nwg & 7;
  int xcd = orig & 7, idx = orig >> 3;
  return (xcd < r ? xcd * (q + 1) : r * (q + 1) + (xcd - r) * q) + idx;
}

// ---------------- fused prep: zero out0 + rope table + all weight transposes ----------------
__global__ void k_prep(const float* __restrict__ w_qkv, const float* __restrict__ w_o,
                       const float* __restrict__ w_ff1, const float* __restrict__ w_ff2,
                       u16* __restrict__ wq_t, u16* __restrict__ wo_t,
                       u16* __restrict__ wf1_t, u16* __restrict__ wf2_t,
                       float* __restrict__ out0, float2* __restrict__ tab) {
  __shared__ float tile[32][33];
  int bid = blockIdx.x;
  int t = threadIdx.x;
  if (bid < 64) {
    int idx = bid * 256 + t;
    out0[idx] = 0.f;
    int n = idx >> 5, i = idx & 31;
    float inv = powf(10000.0f, -(float)i * (1.0f / 32.0f));
    float f = (float)n * inv;
    float s, c;
    sincosf(f, &s, &c);
    tab[idx] = make_float2(c, s);
    return;
  }
  int b2 = bid - 64;
  const float* W;
  u16* Wt;
  int K, N;
  if (b2 < 2304) {
    int l = b2 / 768; b2 -= l * 768;
    W = w_qkv + (size_t)l * D_ * QKV_; Wt = wq_t + (size_t)l * QKV_ * D_;
    K = D_; N = QKV_;
  } else if (b2 < 2816) {
    b2 -= 2304; int l = b2 >> 8; b2 &= 255;
    W = w_o + (size_t)l * D_ * D_; Wt = wo_t + (size_t)l * D_ * D_;
    K = D_; N = D_;
  } else if (b2 < 4864) {
    b2 -= 2816; int l = b2 >> 10; b2 &= 1023;
    W = w_ff1 + (size_t)l * D_ * 4 * D_; Wt = wf1_t + (size_t)l * 4 * D_ * D_;
    K = D_; N = 4 * D_;
  } else {
    b2 -= 4864; int l = b2 >> 10; b2 &= 1023;
    W = w_ff2 + (size_t)l * 4 * D_ * D_; Wt = wf2_t + (size_t)l * D_ * 4 * D_;
    K = 4 * D_; N = D_;
  }
  int nbx = N >> 5;
  int bx = b2 % nbx, by = b2 / nbx;
  int k0 = by * 32, n0 = bx * 32;
  int r = t >> 3, c4 = (t & 7) * 4;
  float4 v = *(const float4*)&W[(size_t)(k0 + r) * N + n0 + c4];
  tile[r][c4] = v.x; tile[r][c4 + 1] = v.y; tile[r][c4 + 2] = v.z; tile[r][c4 + 3] = v.w;
  __syncthreads();
  ushort4 o;
  o.x = f2b(tile[c4 + 0][r]); o.y = f2b(tile[c4 + 1][r]);
  o.z = f2b(tile[c4 + 2][r]); o.w = f2b(tile[c4 + 3][r]);
  *(ushort4*)&Wt[(size_t)(n0 + r) * K + k0 + c4] = o;
}

// ---------------- embedding gather -> bf16 x ----------------
__global__ void k_embed(const int* __restrict__ ids, const float* __restrict__ emb,
                        u16* __restrict__ x) {
  int row = blockIdx.x;
  int id = ids[row];
  float4 v = ((const float4*)(emb + (size_t)id * D_))[threadIdx.x];
  ushort4 o;
  o.x = f2b(v.x); o.y = f2b(v.y); o.z = f2b(v.z); o.w = f2b(v.w);
  ((ushort4*)(x + (size_t)row * D_))[threadIdx.x] = o;
}

// ---------------- row LayerNorm over D=512, bf16 in/out, 4 rows/block ----------------
__global__ void k_ln(const u16* __restrict__ in, const float* __restrict__ gw,
                     const float* __restrict__ bw, u16* __restrict__ out) {
  int row = blockIdx.x * 4 + (threadIdx.x >> 6);
  int lane = threadIdx.x & 63;
  union { bf16x8 v; u16 s[8]; } u;
  u.v = *(const bf16x8*)(in + (size_t)row * D_ + lane * 8);
  float f[8];
#pragma unroll
  for (int j = 0; j < 8; ++j) f[j] = b2f(u.s[j]);
  float s = 0.f, q = 0.f;
#pragma unroll
  for (int j = 0; j < 8; ++j) { s += f[j]; q += f[j] * f[j]; }
#pragma unroll
  for (int o = 32; o >= 1; o >>= 1) {
    s += __shfl_xor(s, o);
    q += __shfl_xor(q, o);
  }
  float mean = s * (1.0f / D_);
  float var = q * (1.0f / D_) - mean * mean;
  float rstd = rsqrtf(var + 1e-5f);
  float4 g0 = *(const float4*)(gw + lane * 8);
  float4 g1 = *(const float4*)(gw + lane * 8 + 4);
  float4 b0 = *(const float4*)(bw + lane * 8);
  float4 b1 = *(const float4*)(bw + lane * 8 + 4);
  float gg[8] = {g0.x, g0.y, g0.z, g0.w, g1.x, g1.y, g1.z, g1.w};
  float bb[8] = {b0.x, b0.y, b0.z, b0.w, b1.x, b1.y, b1.z, b1.w};
  union { bf16x8 v; u16 s[8]; } ov;
#pragma unroll
  for (int j = 0; j < 8; ++j) ov.s[j] = f2b((f[j] - mean) * rstd * gg[j] + bb[j]);
  *(bf16x8*)(out + (size_t)row * D_ + lane * 8) = ov.v;
}

// ---------------- fp32 row LayerNorm (state rows), 4 rows/block ----------------
__global__ void k_lnf(const float* __restrict__ in, const float* __restrict__ gw,
                      const float* __restrict__ bw, float* __restrict__ out) {
  int row = blockIdx.x * 4 + (threadIdx.x >> 6);
  int lane = threadIdx.x & 63;
  const float* p = in + (size_t)row * D_ + lane * 8;
  float4 v0 = *(const float4*)p;
  float4 v1 = *(const float4*)(p + 4);
  float s = v0.x + v0.y + v0.z + v0.w + v1.x + v1.y + v1.z + v1.w;
  float q = v0.x * v0.x + v0.y * v0.y + v0.z * v0.z + v0.w * v0.w +
            v1.x * v1.x + v1.y * v1.y + v1.z * v1.z + v1.w * v1.w;
#pragma unroll
  for (int o = 32; o >= 1; o >>= 1) {
    s += __shfl_xor(s, o);
    q += __shfl_xor(q, o);
  }
  float mean = s * (1.0f / D_);
  float var = q * (1.0f / D_) - mean * mean;
  float rstd = rsqrtf(var + 1e-5f);
  float4 g0 = *(const float4*)(gw + lane * 8);
  float4 g1 = *(const float4*)(gw + lane * 8 + 4);
  float4 b0 = *(const float4*)(bw + lane * 8);
  float4 b1 = *(const float4*)(bw + lane * 8 + 4);
  float* op = out + (size_t)row * D_ + lane * 8;
  *(float4*)op = make_float4((v0.x - mean) * rstd * g0.x + b0.x,
                             (v0.y - mean) * rstd * g0.y + b0.y,
                             (v0.z - mean) * rstd * g0.z + b0.z,
                             (v0.w - mean) * rstd * g0.w + b0.w);
  *(float4*)(op + 4) = make_float4((v1.x - mean) * rstd * g1.x + b1.x,
                                   (v1.y - mean) * rstd * g1.y + b1.y,
                                   (v1.z - mean) * rstd * g1.z + b1.z,
                                   (v1.w - mean) * rstd * g1.w + b1.w);
}

// ---------------- bf16 MFMA GEMM: 128x128, BK=64, counted-vmcnt pipeline ----------------
// T4 applied to the verified R14 kernel: per tile each thread issues 8
// global_load_lds. Iteration it: issue stage(nxt) -> s_waitcnt vmcnt(8)
// (waits only the OLDEST 8 = cur's loads, issued one iteration ago; the 8
// just-issued stay in flight across the barrier) -> raw s_barrier ->
// compute(cur) -> raw s_barrier (cur read-complete, safe to overwrite).
// Last iteration drains vmcnt(0). Layout/swizzle identical (conflicts == 0).
template <int EPI, int BF16OUT>
__global__ __launch_bounds__(256) void k_mgemm(
    const u16* __restrict__ A, const u16* __restrict__ Bt,
    const float* __restrict__ bias, const u16* __restrict__ resid,
    void* __restrict__ Cv, int M, int K, int Nc, int nb0) {
  __shared__ u16 As[2][2][128 * 32];
  __shared__ u16 Bs[2][2][128 * 32];
  int t = threadIdx.x;
  int wave = t >> 6, lane = t & 63;
  int nwg = gridDim.x * gridDim.y;
  int swz = xcd_swz(blockIdx.y * gridDim.x + blockIdx.x, nwg);
  int m0 = (swz / gridDim.x) * 128;
  int n0 = ((swz % gridDim.x) + nb0) * 128;
  int wr = wave >> 1, wc = wave & 1;
  f32x4 acc[4][4] = {};

  int srow = lane >> 2;
  int scol = ((lane & 3) ^ ((lane >> 3) & 3)) * 8;
  const u16* gaBase = A + (size_t)(m0 + wave * 32 + srow) * K + scol;
  const u16* gbBase = Bt + (size_t)(n0 + wave * 32 + srow) * K + scol;

#define STAGE_MG(bsel, sub, kk)                                                \
  {                                                                            \
    _Pragma("unroll") for (int i_ = 0; i_ < 2; ++i_) {                         \
      int rbase_ = wave * 32 + i_ * 16;                                        \
      __builtin_amdgcn_global_load_lds(                                        \
          (const GLOBAL_AS void*)(gaBase + (size_t)(i_ * 16) * K + (kk)),      \
          (LDS_AS void*)&As[bsel][sub][rbase_ * 32], 16, 0, 0);                \
      __builtin_amdgcn_global_load_lds(                                        \
          (const GLOBAL_AS void*)(gbBase + (size_t)(i_ * 16) * K + (kk)),      \
          (LDS_AS void*)&Bs[bsel][sub][rbase_ * 32], 16, 0, 0);                \
    }                                                                          \
  }

  int c = lane & 15, g = lane >> 4;
  int chread = (g ^ ((c >> 1) & 3)) * 8;

  int nIter = K >> 6;
  STAGE_MG(0, 0, 0);
  STAGE_MG(0, 1, 32);
  for (int it = 0; it < nIter; ++it) {
    int cur = it & 1;
    if (it + 1 < nIter) {
      STAGE_MG(cur ^ 1, 0, (size_t)(it + 1) * 64);
      STAGE_MG(cur ^ 1, 1, (size_t)(it + 1) * 64 + 32);
      asm volatile("s_waitcnt vmcnt(8)" ::: "memory");
    } else {
      asm volatile("s_waitcnt vmcnt(0)" ::: "memory");
    }
    __builtin_amdgcn_s_barrier();
#pragma unroll
    for (int sub = 0; sub < 2; ++sub) {
      const u16* as = As[cur][sub];
      const u16* bs = Bs[cur][sub];
      bf16x8 af[4], bfr[4];
#pragma unroll
      for (int mi = 0; mi < 4; ++mi)
        af[mi] = *(const bf16x8*)&as[(wr * 64 + mi * 16 + c) * 32 + chread];
#pragma unroll
      for (int ni = 0; ni < 4; ++ni)
        bfr[ni] = *(const bf16x8*)&bs[(wc * 64 + ni * 16 + c) * 32 + chread];
#pragma unroll
      for (int mi = 0; mi < 4; ++mi)
#pragma unroll
        for (int ni = 0; ni < 4; ++ni)
          acc[mi][ni] = __builtin_amdgcn_mfma_f32_16x16x32_bf16(bfr[ni], af[mi], acc[mi][ni], 0, 0, 0);
    }
    __builtin_amdgcn_s_barrier();
  }
#undef STAGE_MG

#pragma unroll
  for (int mi = 0; mi < 4; ++mi) {
    int m = m0 + wr * 64 + mi * 16 + (lane & 15);
    size_t rowoff = (size_t)m * Nc;
#pragma unroll
    for (int ni = 0; ni < 4; ++ni) {
      int n = n0 + wc * 64 + ni * 16 + (lane >> 4) * 4;
      float v0 = acc[mi][ni][0], v1 = acc[mi][ni][1],
            v2 = acc[mi][ni][2], v3 = acc[mi][ni][3];
      if (EPI == 2 || EPI == 3) {
        float4 bb = *(const float4*)&bias[n];
        v0 += bb.x; v1 += bb.y; v2 += bb.z; v3 += bb.w;
      }
      if (EPI == 2) {
        v0 = gelu_f(v0); v1 = gelu_f(v1); v2 = gelu_f(v2); v3 = gelu_f(v3);
      }
      if (EPI == 1 || EPI == 3) {
        ushort4 rr = *(const ushort4*)&resid[rowoff + n];
        v0 += b2f(rr.x); v1 += b2f(rr.y); v2 += b2f(rr.z); v3 += b2f(rr.w);
      }
      if (BF16OUT) {
        ushort4 o;
        o.x = f2b(v0); o.y = f2b(v1); o.z = f2b(v2); o.w = f2b(v3);
        *(ushort4*)&((u16*)Cv)[rowoff + n] = o;
      } else {
        *(float4*)&((float*)Cv)[rowoff + n] = make_float4(v0, v1, v2, v3);
      }
    }
  }
}

// ---------------- fp32 tiled GEMM (state path, tiny M) ----------------
template <int EPI>
__global__ __launch_bounds__(256) void k_gemm(const float* __restrict__ A,
                                              const float* __restrict__ W,
                                              const float* __restrict__ bias,
                                              const float* __restrict__ resid,
                                              float* __restrict__ C,
                                              int M, int K, int Nc) {
  __shared__ float As[32][68];
  __shared__ float Bs[32][68];
  int t = threadIdx.x;
  int tx = t & 15, ty = t >> 4;
  int m0 = blockIdx.y * 64, n0 = blockIdx.x * 64;
  float acc[4][4] = {};
  int ar = t >> 2, akc = (t & 3) * 8;
  int bkr = t >> 3, bnc = (t & 7) * 8;
  int garow = m0 + ar;
  bool aval = garow < M;
  const float* Aptr = A + (size_t)(aval ? garow : 0) * K + akc;
  const float* Wptr = W + (size_t)bkr * Nc + n0 + bnc;

  for (int k0 = 0; k0 < K; k0 += 32) {
    float4 a0, a1;
    if (aval) {
      a0 = *(const float4*)(Aptr + k0);
      a1 = *(const float4*)(Aptr + k0 + 4);
    } else {
      a0 = make_float4(0.f, 0.f, 0.f, 0.f);
      a1 = a0;
    }
    As[akc + 0][ar] = a0.x; As[akc + 1][ar] = a0.y;
    As[akc + 2][ar] = a0.z; As[akc + 3][ar] = a0.w;
    As[akc + 4][ar] = a1.x; As[akc + 5][ar] = a1.y;
    As[akc + 6][ar] = a1.z; As[akc + 7][ar] = a1.w;
    float4 b0 = *(const float4*)(Wptr + (size_t)k0 * Nc);
    float4 b1 = *(const float4*)(Wptr + (size_t)k0 * Nc + 4);
    *(float4*)&Bs[bkr][bnc] = b0;
    *(float4*)&Bs[bkr][bnc + 4] = b1;
    __syncthreads();
#pragma unroll
    for (int k = 0; k < 32; ++k) {
      float4 av = *(float4*)&As[k][ty * 4];
      float4 bv = *(float4*)&Bs[k][tx * 4];
      float a[4] = {av.x, av.y, av.z, av.w};
      float b[4] = {bv.x, bv.y, bv.z, bv.w};
#pragma unroll
      for (int i = 0; i < 4; ++i)
#pragma unroll
        for (int j = 0; j < 4; ++j) acc[i][j] += a[i] * b[j];
    }
    __syncthreads();
  }
#pragma unroll
  for (int i = 0; i < 4; ++i) {
    int m = m0 + ty * 4 + i;
    if (m >= M) break;
    size_t off = (size_t)m * Nc + n0 + tx * 4;
    float r[4];
#pragma unroll
    for (int j = 0; j < 4; ++j) {
      float v = acc[i][j];
      if (EPI == 2 || EPI == 3) v += bias[n0 + tx * 4 + j];
      if (EPI == 2) v = gelu_f(v);
      if (EPI == 1 || EPI == 3) v += resid[off + j];
      r[j] = v;
    }
    *(float4*)&C[off] = make_float4(r[0], r[1], r[2], r[3]);
  }
}

// ---------------- MFMA flash attention: paired q-tiles + async stage ----------------
__global__ __launch_bounds__(512) void k_fattn(const u16* __restrict__ qkv,
                                               const float2* __restrict__ tab,
                                               u16* __restrict__ out) {
  __shared__ u16 Kl[64 * 64];
  __shared__ u16 Vt[64 * 64];
  __shared__ u16 Pl[8][16 * 64];
  int swz = xcd_swz(blockIdx.x, gridDim.x);
  int p = swz & 1, h = (swz >> 1) & 7, b = swz >> 4;
  int qtA = p, qtB = 3 - p;
  int t = threadIdx.x;
  int w = t >> 6, lane = t & 63;
  int c = lane & 15, g = lane >> 4;

  auto loadQ = [&](int qt, bf16x8* qa) {
    int n = qt * 128 + w * 16 + c;
    const u16* qptr = qkv + (size_t)(b * N_ + n) * QKV_ + h * HD_ + g * 8;
    union { bf16x8 v; u16 s[8]; } a0, a1, r0, r1;
    a0.v = *(const bf16x8*)qptr;
    a1.v = *(const bf16x8*)(qptr + 32);
    const float2* tb = tab + n * 32 + g * 8;
#pragma unroll
    for (int j = 0; j < 8; ++j) {
      float2 cs = tb[j];
      float lo = b2f(a0.s[j]), hi = b2f(a1.s[j]);
      r0.s[j] = f2b((lo * cs.x - hi * cs.y) * SCALE_);
      r1.s[j] = f2b((hi * cs.x + lo * cs.y) * SCALE_);
    }
    qa[0] = r0.v;
    qa[1] = r1.v;
  };

  bf16x8 qaA[2], qaB[2];
  loadQ(qtA, qaA);
  loadQ(qtB, qaB);

  f32x4 OA[4] = {}, OB[4] = {};
  float mA[4], lA[4], mB[4], lB[4];
#pragma unroll
  for (int r = 0; r < 4; ++r) { mA[r] = mB[r] = -1e30f; lA[r] = lB[r] = 0.f; }

  int myA = 2 * qtA + (w >> 2), myB = 2 * qtB + (w >> 2);
  int ktmax = 2 * qtB + 1;

  union { bf16x8 v; u16 s[8]; } rk0, rk1;
  ushort4 rv0a, rv0b, rv1a, rv1b;
  int krow = t >> 2, ki0 = (t & 3) * 8;
  int tt = t - 256, vkp = (tt >> 3) * 2, vd0 = (tt & 7) * 8;

  auto loadT = [&](int kt) {
    if (t < 256) {
      const u16* base = qkv + (size_t)(b * N_ + kt * 64 + krow) * QKV_ + D_ + h * HD_;
      rk0.v = *(const bf16x8*)(base + ki0);
      rk1.v = *(const bf16x8*)(base + ki0 + 32);
    } else {
      const u16* v0p = qkv + (size_t)(b * N_ + kt * 64 + vkp) * QKV_ + 2 * D_ + h * HD_ + vd0;
      const u16* v1p = v0p + QKV_;
      rv0a = *(const ushort4*)v0p;
      rv0b = *(const ushort4*)(v0p + 4);
      rv1a = *(const ushort4*)v1p;
      rv1b = *(const ushort4*)(v1p + 4);
    }
  };

  auto writeT = [&](int kt) {
    if (t < 256) {
      int n = kt * 64 + krow;
      const float2* tb = tab + n * 32 + ki0;
      union { bf16x8 v; u16 s[8]; } olo, ohi;
#pragma unroll
      for (int j = 0; j < 8; ++j) {
        float2 cs = tb[j];
        float fl = b2f(rk0.s[j]), fh = b2f(rk1.s[j]);
        olo.s[j] = f2b(fl * cs.x - fh * cs.y);
        ohi.s[j] = f2b(fh * cs.x + fl * cs.y);
      }
      int bb = krow * 128 + ki0 * 2, sw = (krow & 7) << 4;
      *(bf16x8*)((char*)Kl + (bb ^ sw)) = olo.v;
      *(bf16x8*)((char*)Kl + ((bb + 64) ^ sw)) = ohi.v;
    } else {
      u16 a0[8] = {rv0a.x, rv0a.y, rv0a.z, rv0a.w, rv0b.x, rv0b.y, rv0b.z, rv0b.w};
      u16 a1[8] = {rv1a.x, rv1a.y, rv1a.z, rv1a.w, rv1b.x, rv1b.y, rv1b.z, rv1b.w};
      u32* VtW = (u32*)Vt;
#pragma unroll
      for (int j = 0; j < 8; ++j) {
        int d = vd0 + j;
        VtW[(d * 32 + (vkp >> 1)) ^ ((d & 7) << 2)] = ((u32)a1[j] << 16) | (u32)a0[j];
      }
    }
  };

  auto compute = [&](const bf16x8* qa, f32x4* O, float* m_r, float* l_r,
                     int myblk, int qt, int kt) {
    f32x4 s[4] = {};
#pragma unroll
    for (int ks = 0; ks < 2; ++ks) {
#pragma unroll
      for (int nt = 0; nt < 4; ++nt) {
        int kr = nt * 16 + c;
        int byteoff = (kr * 128 + (g * 8 + ks * 32) * 2) ^ ((kr & 7) << 4);
        bf16x8 kb = *(const bf16x8*)((const char*)Kl + byteoff);
        s[nt] = __builtin_amdgcn_mfma_f32_16x16x32_bf16(qa[ks], kb, s[nt], 0, 0, 0);
      }
    }
    if (kt == myblk) {
#pragma unroll
      for (int nt = 0; nt < 4; ++nt)
#pragma unroll
        for (int r = 0; r < 4; ++r)
          if (kt * 64 + nt * 16 + c > qt * 128 + w * 16 + g * 4 + r) s[nt][r] = -1e30f;
    }
    float tm[4], tl[4], fac[4];
#pragma unroll
    for (int r = 0; r < 4; ++r)
      tm[r] = fmaxf(fmaxf(s[0][r], s[1][r]), fmaxf(s[2][r], s[3][r]));
#pragma unroll
    for (int msk = 1; msk <= 8; msk <<= 1)
#pragma unroll
      for (int r = 0; r < 4; ++r)
        tm[r] = fmaxf(tm[r], __shfl_xor(tm[r], msk));
#pragma unroll
    for (int r = 0; r < 4; ++r) {
      float mn = fmaxf(m_r[r], tm[r]);
      fac[r] = __expf(m_r[r] - mn);
      m_r[r] = mn;
      tl[r] = 0.f;
    }
    u16* plw = Pl[w];
#pragma unroll
    for (int nt = 0; nt < 4; ++nt) {
#pragma unroll
      for (int r = 0; r < 4; ++r) {
        float pv = __expf(s[nt][r] - m_r[r]);
        tl[r] += pv;
        int q = g * 4 + r, kk = nt * 16 + c;
        plw[(q * 64 + kk) ^ ((q & 7) << 3)] = f2b(pv);
      }
    }
#pragma unroll
    for (int msk = 1; msk <= 8; msk <<= 1)
#pragma unroll
      for (int r = 0; r < 4; ++r) tl[r] += __shfl_xor(tl[r], msk);
#pragma unroll
    for (int r = 0; r < 4; ++r) l_r[r] = l_r[r] * fac[r] + tl[r];
#pragma unroll
    for (int nt = 0; nt < 4; ++nt)
#pragma unroll
      for (int r = 0; r < 4; ++r) O[nt][r] *= fac[r];
#pragma unroll
    for (int ks = 0; ks < 2; ++ks) {
      int pbyte = (c * 128 + (g * 8 + ks * 32) * 2) ^ ((c & 7) << 4);
      bf16x8 pa = *(const bf16x8*)((const char*)plw + pbyte);
#pragma unroll
      for (int nt = 0; nt < 4; ++nt) {
        int d = nt * 16 + c;
        int vbyte = (d * 128 + (g * 8 + ks * 32) * 2) ^ ((d & 7) << 4);
        bf16x8 vb = *(const bf16x8*)((const char*)Vt + vbyte);
        O[nt] = __builtin_amdgcn_mfma_f32_16x16x32_bf16(pa, vb, O[nt], 0, 0, 0);
      }
    }
  };

  loadT(0);
  for (int kt = 0; kt <= ktmax; ++kt) {
    writeT(kt);
    __syncthreads();
    if (kt < ktmax) loadT(kt + 1);
    if (kt <= myA) compute(qaA, OA, mA, lA, myA, qtA, kt);
    if (kt <= myB) compute(qaB, OB, mB, lB, myB, qtB, kt);
    __syncthreads();
  }

  auto store = [&](int qt, const f32x4* O, const float* l_r) {
    u16* dst = out + (size_t)(b * N_ + qt * 128 + w * 16) * D_ + h * HD_;
#pragma unroll
    for (int nt = 0; nt < 4; ++nt) {
#pragma unroll
      for (int r = 0; r < 4; ++r) {
        int q = g * 4 + r;
        dst[(size_t)q * D_ + nt * 16 + c] = f2b(O[nt][r] / l_r[r]);
      }
    }
  };
  store(qtA, OA, lA);
  store(qtB, OB, lB);
}

// ---------------- state attention: 1 query, 513 keys, per (b,h); rope k inline ----------------
__global__ __launch_bounds__(128) void k_state_attn(const float* __restrict__ sqkv,
                                                    const u16* __restrict__ qkv,
                                                    const float2* __restrict__ tab,
                                                    float* __restrict__ outs) {
  int h = blockIdx.x, b = blockIdx.y;
  __shared__ float sq[HD_];
  __shared__ float sc[513];
  __shared__ float red[128];
  int t = threadIdx.x;
  if (t < HD_) sq[t] = sqkv[(size_t)b * QKV_ + h * HD_ + t];
  __syncthreads();
  for (int j = t; j < 513; j += 128) {
    float acc = 0.f;
    if (j == 0) {
      const float* kp = sqkv + (size_t)b * QKV_ + D_ + h * HD_;
#pragma unroll
      for (int d = 0; d < HD_; ++d) acc += sq[d] * kp[d];
    } else {
      const u16* kp = qkv + (size_t)(b * N_ + j - 1) * QKV_ + D_ + h * HD_;
      const float2* tb = tab + (size_t)(j - 1) * 32;
#pragma unroll
      for (int d = 0; d < 32; ++d) {
        float2 cs = tb[d];
        float klo = b2f(kp[d]), khi = b2f(kp[d + 32]);
        acc += sq[d] * (klo * cs.x - khi * cs.y) + sq[d + 32] * (khi * cs.x + klo * cs.y);
      }
    }
    sc[j] = acc * SCALE_;
  }
  __syncthreads();
  float m = -1e30f;
  for (int j = t; j < 513; j += 128) m = fmaxf(m, sc[j]);
  red[t] = m;
  __syncthreads();
  for (int s = 64; s > 0; s >>= 1) {
    if (t < s) red[t] = fmaxf(red[t], red[t + s]);
    __syncthreads();
  }
  m = red[0];
  __syncthreads();
  float sum = 0.f;
  for (int j = t; j < 513; j += 128) {
    float p = expf(sc[j] - m);
    sc[j] = p;
    sum += p;
  }
  red[t] = sum;
  __syncthreads();
  for (int s = 64; s > 0; s >>= 1) {
    if (t < s) red[t] += red[t + s];
    __syncthreads();
  }
  float tot = red[0];
  if (t < HD_) {
    int d = t;
    float acc = sc[0] * sqkv[(size_t)b * QKV_ + 2 * D_ + h * HD_ + d];
    for (int j = 1; j <= N_; ++j)
      acc += sc[j] * b2f(qkv[(size_t)(b * N_ + j - 1) * QKV_ + 2 * D_ + h * HD_ + d]);
    outs[(size_t)b * D_ + h * HD_ + d] = acc / tot;
  }
}

// ---------------- gated state update ----------------
__global__ void k_gate(const float* __restrict__ state, const float* __restrict__ upd,
                       const float* __restrict__ beta, float* __restrict__ out2) {
  int idx = blockIdx.x * 256 + threadIdx.x;
  int c = idx & (D_ - 1);
  float g = __builtin_amdgcn_rcpf(1.0f + __expf(-beta[c]));
  out2[idx] = state[idx] * g + upd[idx] * (1.0f - g);
}

// ---------------- host launch ----------------
extern "C" void kernel_launch(void* const* d_in, const int* in_sizes, int n_in,
                              void* d_out, int out_size, void* d_ws, size_t ws_size,
                              hipStream_t stream) {
  (void)in_sizes; (void)n_in; (void)out_size; (void)ws_size;
  const int* ids = (const int*)d_in[0];
  const float* state = (const float*)d_in[1];
  const float* tok_emb = (const float*)d_in[2];
  const float* ln1_g = (const float*)d_in[3];
  const float* ln1_b = (const float*)d_in[4];
  const float* w_qkv = (const float*)d_in[5];
  const float* w_o = (const float*)d_in[6];
  const float* ln2_g = (const float*)d_in[7];
  const float* ln2_b = (const float*)d_in[8];
  const float* w_ff1 = (const float*)d_in[9];
  const float* b_ff1 = (const float*)d_in[10];
  const float* w_ff2 = (const float*)d_in[11];
  const float* b_ff2 = (const float*)d_in[12];
  const float* s_ln_g = (const float*)d_in[13];
  const float* s_ln_b = (const float*)d_in[14];
  const float* w_s_qkv = (const float*)d_in[15];
  const float* w_so = (const float*)d_in[16];
  const float* gate_beta = (const float*)d_in[17];
  // 18..21 dead: log_softmax over size-1 axis is exactly 0 -> output 0 all zeros.

  float* out0 = (float*)d_out;
  float* out1 = (float*)d_out + 16384;

  float* ws = (float*)d_ws;
  u16* x = (u16*)ws;                               // 16384x512 bf16
  u16* qkv_bf = (u16*)(ws + 8388608);              // 16384x1536 bf16 (aliases mid)
  u16* mid_bf = qkv_bf;                            // 16384x2048 bf16 (disjoint liveness)
  u16* h_bf = (u16*)(ws + 25165824);
  u16* ao_bf = (u16*)(ws + 29360128);
  u16* wq_t = (u16*)(ws + 33554432);               // 3 x 1536x512
  u16* wo_t = (u16*)(ws + 34734080);               // 2 x 512x512
  u16* wf1_t = (u16*)(ws + 34996224);              // 2 x 2048x512
  u16* wf2_t = (u16*)(ws + 36044800);              // 2 x 512x2048
  float2* tab = (float2*)(ws + 37191680);          // 512x32 float2 (32768 f)
  float* sln = ws + 37224448;
  float* sqkv = sln + 16384;
  float* souts = sqkv + 49152;
  float* supd = souts + 16384;

  const int M = B_ * N_;  // 16384

  k_prep<<<dim3(6976), dim3(256), 0, stream>>>(w_qkv, w_o, w_ff1, w_ff2,
                                               wq_t, wo_t, wf1_t, wf2_t, out0, tab);
  k_embed<<<dim3(M), dim3(128), 0, stream>>>(ids, tok_emb, x);

  for (int l = 0; l < 3; ++l) {
    k_ln<<<dim3(M / 4), dim3(256), 0, stream>>>(x, ln1_g + l * D_, ln1_b + l * D_, h_bf);
    if (l == 2) {
      // only K,V needed (n0 >= 512): 8 n-blocks with offset 4; rope applied in consumer
      k_mgemm<0, 1><<<dim3(8, 128), dim3(256), 0, stream>>>(
          h_bf, wq_t + (size_t)l * QKV_ * D_, nullptr, nullptr, qkv_bf, M, D_, QKV_, 4);
      break;
    }
    k_mgemm<0, 1><<<dim3(12, 128), dim3(256), 0, stream>>>(
        h_bf, wq_t + (size_t)l * QKV_ * D_, nullptr, nullptr, qkv_bf, M, D_, QKV_, 0);
    k_fattn<<<dim3(2 * H_ * B_), dim3(512), 0, stream>>>(qkv_bf, tab, ao_bf);
    k_mgemm<1, 1><<<dim3(4, 128), dim3(256), 0, stream>>>(
        ao_bf, wo_t + (size_t)l * D_ * D_, nullptr, x, x, M, D_, D_, 0);
    k_ln<<<dim3(M / 4), dim3(256), 0, stream>>>(x, ln2_g + l * D_, ln2_b + l * D_, h_bf);
    k_mgemm<2, 1><<<dim3(16, 128), dim3(256), 0, stream>>>(
        h_bf, wf1_t + (size_t)l * 4 * D_ * D_, b_ff1 + l * 4 * D_, nullptr, mid_bf, M, D_, 4 * D_, 0);
    k_mgemm<3, 1><<<dim3(4, 128), dim3(256), 0, stream>>>(
        mid_bf, wf2_t + (size_t)l * D_ * 4 * D_, b_ff2 + l * D_, x, x, M, 4 * D_, D_, 0);
  }

  // ---- state path at layer REC=2 (qkv_bf holds raw k,v of layer 2; rope inline) ----
  k_lnf<<<dim3(B_ / 4), dim3(256), 0, stream>>>(state, s_ln_g, s_ln_b, sln);
  k_gemm<0><<<dim3(24, 1), dim3(256), 0, stream>>>(
      sln, w_s_qkv, nullptr, nullptr, sqkv, B_, D_, QKV_);
  k_state_attn<<<dim3(H_, B_), dim3(128), 0, stream>>>(sqkv, qkv_bf, tab, souts);
  k_gemm<0><<<dim3(8, 1), dim3(256), 0, stream>>>(
      souts, w_so, nullptr, nullptr, supd, B_, D_, D_);
  k_gate<<<dim3(64), dim3(256), 0, stream>>>(state, supd, gate_beta, out1);
}